// Round 11
// baseline (1579.771 us; speedup 1.0000x reference)
//
#include <hip/hip_runtime.h>
#include <cstddef>

#define EPS 1e-5f
#define NNODE 30000
#define NEDGE 360000
#define NFEAT 92
#define EF 41
#define D 64
#define LAY 3
#define FCW 128
#define NG 64

typedef unsigned short bf16;
typedef __attribute__((ext_vector_type(8))) short short8v;   // 8 bf16 (4 VGPRs) — MFMA A/B frag
typedef __attribute__((ext_vector_type(4))) float float4v;   // MFMA C/D frag

__device__ __forceinline__ float b2f(bf16 u) { return __uint_as_float(((unsigned)u) << 16); }
__device__ __forceinline__ bf16 f2b(float f) {
    unsigned u = __float_as_uint(f);
    unsigned r = (u + 0x7FFFu + ((u >> 16) & 1u)) >> 16;
    return (bf16)r;
}
// fast native transcendentals (v_exp_f32 / v_log_f32 / v_rcp_f32): rel err ~1e-7.
__device__ __forceinline__ float fsp(float x) {       // softplus
    return fmaxf(x, 0.0f) + __logf(1.f + __expf(-fabsf(x)));
}
__device__ __forceinline__ float fsig(float x) {      // sigmoid
    return __builtin_amdgcn_rcpf(1.f + __expf(-x));
}
// packed (gate,scr) dword helpers: low u16 = gate, high u16 = scr
__device__ __forceinline__ float lof(unsigned u) { return __uint_as_float(u << 16); }
__device__ __forceinline__ float hif(unsigned u) { return __uint_as_float(u & 0xffff0000u); }

// ---------------- embedding matmul: pre = X[N,92] @ W[92,64] + b, accumulate col stats
#define EMB_RPB 64
__global__ __launch_bounds__(256) void k_emb_mm(const float* __restrict__ X, const float* __restrict__ W,
                                                const float* __restrict__ bias, float* __restrict__ pre,
                                                float* __restrict__ stats, int N) {
    __shared__ float xs[EMB_RPB][NFEAT];
    __shared__ float red[4][2][64];
    int tid = threadIdx.x;
    int lane = tid & 63, wid = tid >> 6;
    int r0 = blockIdx.x * EMB_RPB;
    float w[NFEAT];
#pragma unroll
    for (int k = 0; k < NFEAT; k++) w[k] = W[k * D + lane];
    float bcol = bias[lane];
    for (int i = tid; i < EMB_RPB * (NFEAT / 4); i += 256) {
        int rr = i / (NFEAT / 4), kk = i - rr * (NFEAT / 4);
        int r = r0 + rr;
        float4 v = (r < N) ? ((const float4*)(X + (size_t)r * NFEAT))[kk] : make_float4(0, 0, 0, 0);
        *(float4*)&xs[rr][kk * 4] = v;
    }
    __syncthreads();
    float s0 = 0.f, s1 = 0.f;
    for (int rr = wid * 16; rr < wid * 16 + 16; rr++) {
        int r = r0 + rr;
        if (r >= N) break;
        float acc = bcol;
#pragma unroll
        for (int k4 = 0; k4 < NFEAT; k4 += 4) {
            float4 xv = *(const float4*)&xs[rr][k4];
            acc += xv.x * w[k4] + xv.y * w[k4 + 1] + xv.z * w[k4 + 2] + xv.w * w[k4 + 3];
        }
        pre[r * D + lane] = acc;
        s0 += acc; s1 += acc * acc;
    }
    red[wid][0][lane] = s0; red[wid][1][lane] = s1;
    __syncthreads();
    if (tid < 64) {
        float a = red[0][0][lane] + red[1][0][lane] + red[2][0][lane] + red[3][0][lane];
        float b = red[0][1][lane] + red[1][1][lane] + red[2][1][lane] + red[3][1][lane];
        atomicAdd(&stats[lane], a);
        atomicAdd(&stats[64 + lane], b);
    }
}

// ---------------- BN + SiLU elementwise
__global__ void k_bnsilu(const float* __restrict__ pre, const float* __restrict__ stats,
                         const float* __restrict__ g, const float* __restrict__ beta,
                         float* __restrict__ h, int N, float invn) {
    int idx = blockIdx.x * blockDim.x + threadIdx.x;
    int total = N * D / 4;
    if (idx >= total) return;
    int c0 = (idx * 4) & 63;
    float4 p = ((const float4*)pre)[idx];
    float pv[4] = {p.x, p.y, p.z, p.w}, o[4];
#pragma unroll
    for (int t = 0; t < 4; t++) {
        int c = c0 + t;
        float m = stats[c] * invn;
        float v = stats[64 + c] * invn - m * m;
        float sc = g[c] * rsqrtf(fmaxf(v, 0.f) + EPS);
        float sh = beta[c] - m * sc;
        float y = sc * pv[t] + sh;
        o[t] = y * fsig(y);
    }
    ((float4*)h)[idx] = make_float4(o[0], o[1], o[2], o[3]);
}

// ---------------- pack edge weights: WT[layer][c][k] = bf16(W_ef[k][c]), c: 0..63 gate, 64..127 scr; k padded 41->64
__global__ void k_wpack(const float* __restrict__ convW, bf16* __restrict__ WT3) {
    int layer = blockIdx.x;
    const float* Wc = convW + (size_t)layer * 2 * 169 * 64;
    bf16* WT = WT3 + (size_t)layer * 128 * 64;
    for (int i = threadIdx.x; i < 128 * 64; i += blockDim.x) {
        int c = i >> 6, k = i & 63;
        float v = 0.f;
        if (k < EF) v = (c < 64) ? Wc[(128 + k) * 64 + c] : Wc[169 * 64 + (128 + k) * 64 + (c - 64)];
        WT[i] = f2b(v);
    }
}

// ---------------- CSR build: histogram -> block scan (deg -> cursor) -> fill (pos + DSTO)
__global__ void k_hist(const int* __restrict__ dst, int* __restrict__ deg, int E) {
    int i = blockIdx.x * blockDim.x + threadIdx.x;
    if (i < E) atomicAdd(&deg[dst[i]], 1);
}

__global__ __launch_bounds__(1024) void k_scan(int* __restrict__ deg, int N) {
    __shared__ int ls[1024];
    int tid = threadIdx.x;
    const int CH = (NNODE + 1023) / 1024;   // 30
    int base = tid * CH;
    int s = 0;
    for (int k = 0; k < CH; k++) {
        int i = base + k;
        if (i < N) s += deg[i];
    }
    ls[tid] = s;
    __syncthreads();
    for (int off = 1; off < 1024; off <<= 1) {
        int v = (tid >= off) ? ls[tid - off] : 0;
        __syncthreads();
        ls[tid] += v;
        __syncthreads();
    }
    int run = (tid == 0) ? 0 : ls[tid - 1];
    for (int k = 0; k < CH; k++) {
        int i = base + k;
        if (i < N) {
            int d = deg[i];
            deg[i] = run;        // exclusive prefix = fill cursor
            run += d;
        }
    }
}

__global__ void k_fill(const int* __restrict__ dst, int* __restrict__ cur, int* __restrict__ pos,
                       int* __restrict__ DSTO, int E) {
    int i = blockIdx.x * blockDim.x + threadIdx.x;
    if (i < E) {
        int p = atomicAdd(&cur[dst[i]], 1);
        pos[i] = p;
        DSTO[p] = dst[i];
    }
}

// ---------------- reorder (once per branch): coalesced ef read -> LDS bf16 stage -> FULL-LINE scatter
__global__ __launch_bounds__(256) void k_reord3(const float* __restrict__ ef, const int* __restrict__ src,
                                                const int* __restrict__ pos,
                                                bf16* __restrict__ EFR, int* __restrict__ SRCO, int E) {
    __shared__ bf16 stg[4][8][64];                     // 4 KB: 8 staged rows per wave
    int tid = threadIdx.x, lane = tid & 63, wid = tid >> 6;
    int e0 = (blockIdx.x * 4 + wid) * 8;               // wave's 8 edges (E % 32 == 0)
    if (e0 >= E) return;
    for (int i = lane; i < 512; i += 64) ((bf16*)stg[wid])[i] = 0;   // zero incl. k=41..63 pad
    __builtin_amdgcn_wave_barrier();
    const float* base = ef + (size_t)e0 * EF;
    for (int i = lane; i < 8 * EF; i += 64) {          // 328 dwords, coalesced
        float v = base[i];
        int r = i / EF, k = i - r * EF;
        stg[wid][r][k] = f2b(v);
    }
    __builtin_amdgcn_wave_barrier();
    int r = lane >> 3, sub = lane & 7;
    int p = pos[e0 + r];                               // 8 distinct, octet-broadcast
    uint4 val = *(const uint4*)&stg[wid][r][sub * 8];
    *(uint4*)(EFR + (size_t)p * 64 + sub * 8) = val;   // 8 lanes/row -> one full 128B line per row
    if (sub == 0) SRCO[p] = src[e0 + r];
}

// ---------------- node projections (MODE 1: fused h = softplus(BN(upd_prev)+h) applied in-place
// while staging). Packed output SRCP/DSTP; zeroes upd_cur for the subsequent apply pass.
#define NP_RPB 64
template <int MODE>
__global__ __launch_bounds__(256) void k_nodeproj(float* __restrict__ h, const float* __restrict__ Wc,
                                                  unsigned* __restrict__ SRCP, unsigned* __restrict__ DSTP,
                                                  const float* __restrict__ updp, const float* __restrict__ ustats,
                                                  const float* __restrict__ ng, const float* __restrict__ nb,
                                                  float* __restrict__ updz, int N, float invn) {
    __shared__ float hs[NP_RPB][D];
    int tid = threadIdx.x;
    for (int i = blockIdx.x * 256 + tid; i < N * D / 4; i += gridDim.x * 256)
        ((float4*)updz)[i] = make_float4(0.f, 0.f, 0.f, 0.f);
    // hoisted BN consts for fused updapply: kk = tid & 15 is loop-invariant -> 4 fixed cols
    float sc_[4], sh_[4];
    if (MODE) {
        int kk0 = tid & 15;
#pragma unroll
        for (int t = 0; t < 4; t++) {
            int c = kk0 * 4 + t;
            float m = ustats[c] * invn, v = ustats[64 + c] * invn - m * m;
            sc_[t] = ng[c] * rsqrtf(fmaxf(v, 0.f) + EPS);
            sh_[t] = nb[c] - m * sc_[t];
        }
    }
    int j = tid & 63;
    int mat = tid >> 6;          // 0: src-gate 1: src-scr 2: dst-gate 3: dst-scr
    int jj = mat & 1;
    int roff = (mat >> 1) * 64;
    const float* Wb = Wc + ((size_t)jj * 169 + roff) * 64 + j;
    float w[D];
#pragma unroll
    for (int k = 0; k < D; k++) w[k] = Wb[k * 64];
    int r0 = blockIdx.x * NP_RPB;
    for (int i = tid; i < NP_RPB * D / 4; i += 256) {
        int rr = i >> 4, kk = (i & 15);
        int r = r0 + rr;
        float4 v = make_float4(0, 0, 0, 0);
        if (r < N) {
            v = ((const float4*)(h + (size_t)r * D))[kk];
            if (MODE) {
                float4 u = ((const float4*)(updp + (size_t)r * D))[kk];
                float uv[4] = {u.x, u.y, u.z, u.w}, hv[4] = {v.x, v.y, v.z, v.w};
#pragma unroll
                for (int t = 0; t < 4; t++) hv[t] = fsp(sc_[t] * uv[t] + sh_[t] + hv[t]);
                v = make_float4(hv[0], hv[1], hv[2], hv[3]);
                ((float4*)(h + (size_t)r * D))[kk] = v;   // in-place; each element touched once
            }
        }
        *(float4*)&hs[rr][kk * 4] = v;
    }
    __syncthreads();
    unsigned short* out = (unsigned short*)((mat < 2) ? SRCP : DSTP);
    int rmax = min(NP_RPB, N - r0);
    for (int rr = 0; rr < rmax; rr++) {
        float acc = 0.f;
#pragma unroll
        for (int k4 = 0; k4 < D; k4 += 4) {
            float4 xv = *(const float4*)&hs[rr][k4];
            acc += xv.x * w[k4] + xv.y * w[k4 + 1] + xv.z * w[k4 + 2] + xv.w * w[k4 + 3];
        }
        out[(size_t)(r0 + rr) * 128 + j * 2 + jj] = f2b(acc);
    }
}

// ---------------- edge pass 1 (stats only): src staged in LDS (random rows, coalesced uint4);
// dst loaded DIRECT (CSR-sorted -> 1-3 distinct rows/tile -> L1 hits). Per-block plain-store partial.
#define ESTATS_BLOCKS 2048
__global__ __launch_bounds__(256) void k_estats(const bf16* __restrict__ EFR, const bf16* __restrict__ WT,
                                                const int* __restrict__ SRCO, const int* __restrict__ DSTO,
                                                const unsigned* __restrict__ SRCP, const unsigned* __restrict__ DSTP,
                                                float* __restrict__ PARTIAL) {
    __shared__ float red[4][4][64];
    __shared__ unsigned stg_[4][16][68];               // src only; stride 68 -> 2-way (free)
    int tid = threadIdx.x, lane = tid & 63, wid = tid >> 6;
    int lr = lane & 15, lg = lane >> 4;
    float stg[4], sqg[4], sts_[4], sqs[4];
#pragma unroll
    for (int t = 0; t < 4; t++) { stg[t] = 0.f; sqg[t] = 0.f; sts_[t] = 0.f; sqs[t] = 0.f; }
    int gw = blockIdx.x * 4 + wid, nw = gridDim.x * 4;
    const int NT = NEDGE / 16;                         // 22500 tiles
    for (int tile = gw; tile < NT; tile += nw) {
        int p0 = tile * 16;
        const bf16* arow = EFR + (size_t)(p0 + lr) * 64;   // 128B-aligned row
        short8v a0 = __builtin_nontemporal_load((const short8v*)(arow + lg * 8));
        short8v a1 = __builtin_nontemporal_load((const short8v*)(arow + 32 + lg * 8));  // k 41..63 zero
        int sidx[4];
#pragma unroll
        for (int i = 0; i < 4; i++) sidx[i] = SRCO[p0 + 4 * i + lg];
        uint4 sv4[4];
#pragma unroll
        for (int i = 0; i < 4; i++) sv4[i] = ((const uint4*)(SRCP + (size_t)sidx[i] * 64))[lr];
        int didx[4];                                   // dst of this lane's 4 consumption rows
#pragma unroll
        for (int j = 0; j < 4; j++) didx[j] = DSTO[p0 + lg * 4 + j];
        unsigned ud[4][4];                             // [t][j] direct loads, L1-hot (dst runs)
#pragma unroll
        for (int t = 0; t < 4; t++)
#pragma unroll
            for (int j = 0; j < 4; j++) ud[t][j] = DSTP[(size_t)didx[j] * 64 + 16 * t + lr];
        __builtin_amdgcn_sched_barrier(0);
#pragma unroll
        for (int i = 0; i < 4; i++) *(uint4*)&stg_[wid][4 * i + lg][4 * lr] = sv4[i];
        __builtin_amdgcn_wave_barrier();
#pragma unroll
        for (int t = 0; t < 4; t++) {
            const bf16* wg = WT + (size_t)(16 * t + lr) * 64 + lg * 8;
            const bf16* wsc = WT + (size_t)(64 + 16 * t + lr) * 64 + lg * 8;
            float4v accg = {0.f, 0.f, 0.f, 0.f}, accs = {0.f, 0.f, 0.f, 0.f};
            accg = __builtin_amdgcn_mfma_f32_16x16x32_bf16(a0, *(const short8v*)wg, accg, 0, 0, 0);
            accg = __builtin_amdgcn_mfma_f32_16x16x32_bf16(a1, *(const short8v*)(wg + 32), accg, 0, 0, 0);
            accs = __builtin_amdgcn_mfma_f32_16x16x32_bf16(a0, *(const short8v*)wsc, accs, 0, 0, 0);
            accs = __builtin_amdgcn_mfma_f32_16x16x32_bf16(a1, *(const short8v*)(wsc + 32), accs, 0, 0, 0);
            int cl = 16 * t + lr;
#pragma unroll
            for (int j = 0; j < 4; j++) {
                int row = lg * 4 + j;                  // C/D: row = (lane>>4)*4 + reg, col = lane&15
                unsigned usv = stg_[wid][row][cl];
                unsigned udv = ud[t][j];
                float pg = accg[j] + lof(usv) + lof(udv);
                float ps = accs[j] + hif(usv) + hif(udv);
                stg[t] += pg; sqg[t] += pg * pg; sts_[t] += ps; sqs[t] += ps * ps;
            }
        }
        __builtin_amdgcn_wave_barrier();               // LDS WAR fence before next-iter overwrite
    }
#pragma unroll
    for (int t = 0; t < 4; t++) {
        float v0 = stg[t], v1 = sqg[t], v2 = sts_[t], v3 = sqs[t];
        v0 += __shfl_xor(v0, 16); v0 += __shfl_xor(v0, 32);
        v1 += __shfl_xor(v1, 16); v1 += __shfl_xor(v1, 32);
        v2 += __shfl_xor(v2, 16); v2 += __shfl_xor(v2, 32);
        v3 += __shfl_xor(v3, 16); v3 += __shfl_xor(v3, 32);
        if (lg == 0) {
            red[wid][0][16 * t + lr] = v0; red[wid][1][16 * t + lr] = v1;
            red[wid][2][16 * t + lr] = v2; red[wid][3][16 * t + lr] = v3;
        }
    }
    __syncthreads();
    if (tid < 64) {
#pragma unroll
        for (int q = 0; q < 4; q++) {
            float v = red[0][q][lane] + red[1][q][lane] + red[2][q][lane] + red[3][q][lane];
            PARTIAL[(size_t)blockIdx.x * 256 + q * 64 + lane] = v;   // plain store, no hotspot
        }
    }
}

// ---------------- reduce per-block partials into stats (128 blocks x 16 unrolled coalesced rows)
#define RED_BLOCKS 128
__global__ __launch_bounds__(256) void k_redstats(const float* __restrict__ PARTIAL, float* __restrict__ stats) {
    int j = threadIdx.x;
    const int R = ESTATS_BLOCKS / RED_BLOCKS;          // 16
    const float* p = PARTIAL + (size_t)blockIdx.x * R * 256 + j;
    float s = 0.f;
#pragma unroll
    for (int k = 0; k < R; k++) s += p[(size_t)k * 256];
    atomicAdd(&stats[j], s);
}

// ---------------- edge pass 2 (recompute + apply + dst-run segmented scatter), grid-stride tiles.
__global__ __launch_bounds__(256) void k_eapply2(const bf16* __restrict__ EFR, const bf16* __restrict__ WT,
                                                 const int* __restrict__ SRCO, const int* __restrict__ DSTO,
                                                 const unsigned* __restrict__ SRCP, const unsigned* __restrict__ DSTP,
                                                 const float* __restrict__ stats,
                                                 const float* __restrict__ gg, const float* __restrict__ gb,
                                                 const float* __restrict__ sg, const float* __restrict__ sb,
                                                 float* __restrict__ upd) {
    __shared__ unsigned stg_[4][16][68];               // src only
    int tid = threadIdx.x, lane = tid & 63, wid = tid >> 6;
    int lr = lane & 15, lg = lane >> 4;
    float invE = 1.0f / (float)NEDGE;
    float scg[4], shg[4], scs[4], shs[4];
#pragma unroll
    for (int t = 0; t < 4; t++) {
        int col = 16 * t + lr;
        float m = stats[col] * invE;
        float v = stats[64 + col] * invE - m * m;
        scg[t] = gg[col] * rsqrtf(fmaxf(v, 0.f) + EPS);
        shg[t] = gb[col] - m * scg[t];
        m = stats[128 + col] * invE;
        v = stats[192 + col] * invE - m * m;
        scs[t] = sg[col] * rsqrtf(fmaxf(v, 0.f) + EPS);
        shs[t] = sb[col] - m * scs[t];
    }
    int gw = blockIdx.x * 4 + wid, nw = gridDim.x * 4;
    const int NT = NEDGE / 16;
    for (int tile = gw; tile < NT; tile += nw) {
        int p0 = tile * 16;
        const bf16* arow = EFR + (size_t)(p0 + lr) * 64;
        short8v a0 = __builtin_nontemporal_load((const short8v*)(arow + lg * 8));
        short8v a1 = __builtin_nontemporal_load((const short8v*)(arow + 32 + lg * 8));
        int sidx[4];
#pragma unroll
        for (int i = 0; i < 4; i++) sidx[i] = SRCO[p0 + 4 * i + lg];
        uint4 sv4[4];
#pragma unroll
        for (int i = 0; i < 4; i++) sv4[i] = ((const uint4*)(SRCP + (size_t)sidx[i] * 64))[lr];
        int didx[4];
#pragma unroll
        for (int j = 0; j < 4; j++) didx[j] = DSTO[p0 + lg * 4 + j];
        unsigned ud[4][4];
#pragma unroll
        for (int t = 0; t < 4; t++)
#pragma unroll
            for (int j = 0; j < 4; j++) ud[t][j] = DSTP[(size_t)didx[j] * 64 + 16 * t + lr];
        __builtin_amdgcn_sched_barrier(0);
#pragma unroll
        for (int i = 0; i < 4; i++) *(uint4*)&stg_[wid][4 * i + lg][4 * lr] = sv4[i];
        __builtin_amdgcn_wave_barrier();
        float acts[4][4];
#pragma unroll
        for (int t = 0; t < 4; t++) {
            const bf16* wg = WT + (size_t)(16 * t + lr) * 64 + lg * 8;
            const bf16* wsc = WT + (size_t)(64 + 16 * t + lr) * 64 + lg * 8;
            float4v accg = {0.f, 0.f, 0.f, 0.f}, accs = {0.f, 0.f, 0.f, 0.f};
            accg = __builtin_amdgcn_mfma_f32_16x16x32_bf16(a0, *(const short8v*)wg, accg, 0, 0, 0);
            accg = __builtin_amdgcn_mfma_f32_16x16x32_bf16(a1, *(const short8v*)(wg + 32), accg, 0, 0, 0);
            accs = __builtin_amdgcn_mfma_f32_16x16x32_bf16(a0, *(const short8v*)wsc, accs, 0, 0, 0);
            accs = __builtin_amdgcn_mfma_f32_16x16x32_bf16(a1, *(const short8v*)(wsc + 32), accs, 0, 0, 0);
            int cl = 16 * t + lr;
#pragma unroll
            for (int j = 0; j < 4; j++) {
                int row = lg * 4 + j;
                unsigned usv = stg_[wid][row][cl];
                unsigned udv = ud[t][j];
                float pg = accg[j] + lof(usv) + lof(udv);
                float ps = accs[j] + hif(usv) + hif(udv);
                float yg = scg[t] * pg + shg[t], ys = scs[t] * ps + shs[t];
                acts[t][j] = fsp(ys) * fsig(yg);       // native exp/log/rcp
            }
        }
        // dst-run segmented reduction over the tile's 16 rows (dst-sorted -> few runs)
        int dval = DSTO[p0 + (lane & 15)];
        int prev = __shfl(dval, (lane == 0) ? 0 : lane - 1);
        unsigned long long bal = __ballot(lane < 16 && lane > 0 && dval != prev);
        unsigned mask = (unsigned)bal & 0xFFFFu;
        int a = 0;
        while (a < 16) {
            unsigned mm = mask & ~((2u << a) - 1);
            int b = mm ? __builtin_ctz(mm) : 16;
            int n = __shfl(dval, a);
#pragma unroll
            for (int t = 0; t < 4; t++) {
                float pp = 0.f;
#pragma unroll
                for (int j = 0; j < 4; j++) {
                    int row = lg * 4 + j;
                    if (row >= a && row < b) pp += acts[t][j];
                }
                pp += __shfl_xor(pp, 16);
                pp += __shfl_xor(pp, 32);
                if (lg == 0) atomicAdd(&upd[(size_t)n * 64 + 16 * t + lr], pp);
            }
            a = b;
        }
        __builtin_amdgcn_wave_barrier();               // LDS WAR fence before next-iter overwrite
    }
}

// ---------------- column stats of upd
__global__ __launch_bounds__(256) void k_colstats(const float* __restrict__ x, float* __restrict__ stats, int N) {
    int tid = threadIdx.x, lane = tid & 63, wid = tid >> 6;
    __shared__ float red[4][2][64];
    float s = 0, q = 0;
    int gw = blockIdx.x * 4 + wid, nw = gridDim.x * 4;
    for (int r = gw; r < N; r += nw) {
        float v = x[(size_t)r * D + lane];
        s += v; q += v * v;
    }
    red[wid][0][lane] = s; red[wid][1][lane] = q;
    __syncthreads();
    if (tid < 64) {
        float a = red[0][0][lane] + red[1][0][lane] + red[2][0][lane] + red[3][0][lane];
        float b = red[0][1][lane] + red[1][1][lane] + red[2][1][lane] + red[3][1][lane];
        atomicAdd(&stats[lane], a);
        atomicAdd(&stats[64 + lane], b);
    }
}

// ---------------- segment-sum pool (batch sorted); MODE 1 fuses final h = softplus(BN(upd)+h)
template <int MODE>
__global__ __launch_bounds__(256) void k_pool(const float* __restrict__ h, const int* __restrict__ batch,
                                              const float* __restrict__ upd, const float* __restrict__ ustats,
                                              const float* __restrict__ ng, const float* __restrict__ nb,
                                              float* __restrict__ pool, float* __restrict__ cnt, int N, float invn) {
    int tid = threadIdx.x, lane = tid & 63, wid = tid >> 6;
    float sc = 0.f, sh = 0.f;
    if (MODE) {
        float m = ustats[lane] * invn, v = ustats[64 + lane] * invn - m * m;
        sc = ng[lane] * rsqrtf(fmaxf(v, 0.f) + EPS);
        sh = nb[lane] - m * sc;
    }
    int w = blockIdx.x * 4 + wid, nw = gridDim.x * 4;
    int chunk = (N + nw - 1) / nw;
    int r0 = w * chunk, r1 = min(N, r0 + chunk);
    if (r0 >= r1) return;
    int cur = batch[r0];
    float acc = 0.f, c = 0.f;
    for (int r = r0; r < r1; r++) {
        int b = batch[r];
        if (b != cur) {
            atomicAdd(&pool[(size_t)cur * D + lane], acc);
            if (lane == 0) atomicAdd(&cnt[cur], c);
            acc = 0.f; c = 0.f; cur = b;
        }
        float hv = h[(size_t)r * D + lane];
        if (MODE) hv = fsp(sc * upd[(size_t)r * D + lane] + sh + hv);
        acc += hv;
        c += 1.f;
    }
    atomicAdd(&pool[(size_t)cur * D + lane], acc);
    if (lane == 0) atomicAdd(&cnt[cur], c);
}

// ---------------- fc
__global__ __launch_bounds__(128) void k_fc(const float* __restrict__ pool, const float* __restrict__ cnt,
                                            const float* __restrict__ fcW, const float* __restrict__ fcb,
                                            float* __restrict__ Y, float* __restrict__ ystats) {
    int g = blockIdx.x;
    int j = threadIdx.x;
    __shared__ float vt[FCW];
    {
        float s, c;
        if (j < 64) { s = pool[(size_t)g * D + j]; c = cnt[g]; }
        else { s = pool[4096 + (size_t)g * D + (j - 64)]; c = cnt[64 + g]; }
        vt[j] = s / fmaxf(c, 1.0f);
    }
    __syncthreads();
    float acc = fcb[j];
#pragma unroll
    for (int k4 = 0; k4 < FCW; k4 += 4) {
        float4 v = *(const float4*)&vt[k4];
        acc += v.x * fcW[(k4 + 0) * FCW + j] + v.y * fcW[(k4 + 1) * FCW + j] +
               v.z * fcW[(k4 + 2) * FCW + j] + v.w * fcW[(k4 + 3) * FCW + j];
    }
    Y[(size_t)g * FCW + j] = acc;
    atomicAdd(&ystats[j], acc);
    atomicAdd(&ystats[128 + j], acc * acc);
}

// ---------------- head
__global__ __launch_bounds__(128) void k_head(const float* __restrict__ Y, const float* __restrict__ ystats,
                                              const float* __restrict__ fg, const float* __restrict__ fb,
                                              const float* __restrict__ pW, const float* __restrict__ pb,
                                              float* __restrict__ out) {
    int j = threadIdx.x;
    __shared__ float ys[NG][FCW + 1];
    __shared__ float pw[FCW];
    float invn = 1.0f / (float)NG;
    float m = ystats[j] * invn, v = ystats[128 + j] * invn - m * m;
    float sc = fg[j] * rsqrtf(fmaxf(v, 0.f) + EPS);
    float sh = fb[j] - m * sc;
    for (int g = 0; g < NG; g++) {
        float y = sc * Y[(size_t)g * FCW + j] + sh;
        ys[g][j] = y * fsig(y);
    }
    pw[j] = pW[j];
    __syncthreads();
    if (j < NG) {
        float acc = pb[0];
        for (int k = 0; k < FCW; k++) acc += ys[j][k] * pw[k];
        out[j] = acc;
    }
}

// ---------------- workspace layout (bytes) — total ~92.2 MB <= granted 130,658,304
static const size_t OFF_EMBSTATS = 0;                    // [2][128] f32
static const size_t OFF_EDGESTATS = 1024;                // [6][256] f32
static const size_t OFF_UPDSTATS = 7168;                 // [6][128] f32
static const size_t OFF_POOL = 10240;                    // [2][4096] f32
static const size_t OFF_CNT = 43008;                     // [2][64] f32
static const size_t OFF_YSTATS = 43520;                  // [256] f32
static const size_t STATS_BYTES = 44544;
static const size_t OFF_H = 65536;                       // 7,680,000
static const size_t OFF_SCRATCH = OFF_H + 7680000;       // emb preact; then WT3/Y/DEG/POS/DSTO/PARTIAL
static const size_t OFF_UPD0 = OFF_SCRATCH + 7680000;    // ping-pong upd
static const size_t OFF_UPD1 = OFF_UPD0 + 7680000;
static const size_t OFF_SRCP = OFF_UPD1 + 7680000;       // uint [30000][64]
static const size_t OFF_DSTP = OFF_SRCP + 7680000;
static const size_t OFF_EFR = OFF_DSTP + 7680000;        // bf16 [360000][64] = 46,080,000 -> ends 92,225,536
// sub-layout of SCRATCH after bnsilu frees it:
static const size_t SC_WT3 = 0;          // 49152
static const size_t SC_Y = 49152;        // 32768
static const size_t SC_DEG = 81920;      // 120000
static const size_t SC_POS = 204800;     // 1,440,000
static const size_t SC_SRCO = 1644800;   // 1,440,000
static const size_t SC_DSTO = 3084800;   // 1,440,000
static const size_t SC_PART = 4524800;   // 2048*256*4 = 2,097,152 -> ends 6,621,952 < 7,680,000

extern "C" void kernel_launch(void* const* d_in, const int* in_sizes, int n_in,
                              void* d_out, int out_size, void* d_ws, size_t ws_size,
                              hipStream_t stream) {
    char* ws = (char*)d_ws;
    hipMemsetAsync(d_ws, 0, STATS_BYTES, stream);

    float* h = (float*)(ws + OFF_H);
    float* scratch = (float*)(ws + OFF_SCRATCH);
    bf16* WT3 = (bf16*)(ws + OFF_SCRATCH + SC_WT3);
    float* Y = (float*)(ws + OFF_SCRATCH + SC_Y);
    int* DEG = (int*)(ws + OFF_SCRATCH + SC_DEG);
    int* POS = (int*)(ws + OFF_SCRATCH + SC_POS);
    int* SRCO = (int*)(ws + OFF_SCRATCH + SC_SRCO);
    int* DSTO = (int*)(ws + OFF_SCRATCH + SC_DSTO);
    float* PARTIAL = (float*)(ws + OFF_SCRATCH + SC_PART);
    float* updbuf[2] = {(float*)(ws + OFF_UPD0), (float*)(ws + OFF_UPD1)};
    unsigned* SRCP = (unsigned*)(ws + OFF_SRCP);
    unsigned* DSTP = (unsigned*)(ws + OFF_DSTP);
    bf16* EFR = (bf16*)(ws + OFF_EFR);

    const int NPGRID = (NNODE + NP_RPB - 1) / NP_RPB;

    for (int br = 0; br < 2; br++) {
        const float* vf = (const float*)d_in[br ? 2 : 0];
        const float* ef = (const float*)d_in[br ? 3 : 1];
        const int* srci = (const int*)d_in[br ? 7 : 4];
        const int* dsti = (const int*)d_in[br ? 8 : 5];
        const int* bat = (const int*)d_in[br ? 9 : 6];
        const float* embW = (const float*)d_in[br ? 14 : 10];
        const float* embB = (const float*)d_in[br ? 15 : 11];
        const float* embG = (const float*)d_in[br ? 16 : 12];
        const float* embBe = (const float*)d_in[br ? 17 : 13];
        const float* convW = (const float*)d_in[br ? 24 : 18];
        const float* convG = (const float*)d_in[br ? 26 : 20];
        const float* convBe = (const float*)d_in[br ? 27 : 21];
        const float* convNG = (const float*)d_in[br ? 28 : 22];
        const float* convNB = (const float*)d_in[br ? 29 : 23];

        float* embstats = (float*)(ws + OFF_EMBSTATS) + br * 128;
        float* poolp = (float*)(ws + OFF_POOL) + br * 4096;
        float* cntp = (float*)(ws + OFF_CNT) + br * 64;

        k_emb_mm<<<(NNODE + EMB_RPB - 1) / EMB_RPB, 256, 0, stream>>>(vf, embW, embB, scratch, embstats, NNODE);
        k_bnsilu<<<NNODE * D / 4 / 256, 256, 0, stream>>>(scratch, embstats, embG, embBe, h, NNODE, 1.0f / NNODE);
        // scratch region now repurposed (rebuilt per branch)
        k_wpack<<<3, 256, 0, stream>>>(convW, WT3);
        hipMemsetAsync(DEG, 0, NNODE * 4, stream);
        k_hist<<<(NEDGE + 255) / 256, 256, 0, stream>>>(dsti, DEG, NEDGE);
        k_scan<<<1, 1024, 0, stream>>>(DEG, NNODE);
        k_fill<<<(NEDGE + 255) / 256, 256, 0, stream>>>(dsti, DEG, POS, DSTO, NEDGE);
        k_reord3<<<NEDGE / 32, 256, 0, stream>>>(ef, srci, POS, EFR, SRCO, NEDGE);

        for (int i = 0; i < LAY; i++) {
            const float* Wc = convW + (size_t)i * 2 * 169 * 64;
            const bf16* WT = WT3 + (size_t)i * 128 * 64;
            float* estats = (float*)(ws + OFF_EDGESTATS) + (br * 3 + i) * 256;
            float* ustats = (float*)(ws + OFF_UPDSTATS) + (br * 3 + i) * 128;
            const float* gg = convG + (i * 2 + 0) * 64;
            const float* gb = convBe + (i * 2 + 0) * 64;
            const float* sg = convG + (i * 2 + 1) * 64;
            const float* sb = convBe + (i * 2 + 1) * 64;
            float* updc = updbuf[i & 1];

            if (i == 0) {
                k_nodeproj<0><<<NPGRID, 256, 0, stream>>>(h, Wc, SRCP, DSTP, nullptr, nullptr, nullptr, nullptr,
                                                          updc, NNODE, 1.0f / NNODE);
            } else {
                float* ustatsp = (float*)(ws + OFF_UPDSTATS) + (br * 3 + i - 1) * 128;
                k_nodeproj<1><<<NPGRID, 256, 0, stream>>>(h, Wc, SRCP, DSTP, updbuf[(i - 1) & 1], ustatsp,
                                                          convNG + (i - 1) * 64, convNB + (i - 1) * 64,
                                                          updc, NNODE, 1.0f / NNODE);
            }
            k_estats<<<ESTATS_BLOCKS, 256, 0, stream>>>(EFR, WT, SRCO, DSTO, SRCP, DSTP, PARTIAL);
            k_redstats<<<RED_BLOCKS, 256, 0, stream>>>(PARTIAL, estats);
            k_eapply2<<<2048, 256, 0, stream>>>(EFR, WT, SRCO, DSTO, SRCP, DSTP, estats, gg, gb, sg, sb, updc);
            k_colstats<<<512, 256, 0, stream>>>(updc, ustats, NNODE);
        }
        {
            float* ustatsl = (float*)(ws + OFF_UPDSTATS) + (br * 3 + LAY - 1) * 128;
            k_pool<1><<<128, 256, 0, stream>>>(h, bat, updbuf[(LAY - 1) & 1], ustatsl,
                                               convNG + (LAY - 1) * 64, convNB + (LAY - 1) * 64,
                                               poolp, cntp, NNODE, 1.0f / NNODE);
        }
    }

    float* poolall = (float*)(ws + OFF_POOL);
    float* cntall = (float*)(ws + OFF_CNT);
    float* ystats = (float*)(ws + OFF_YSTATS);
    k_fc<<<64, 128, 0, stream>>>(poolall, cntall, (const float*)d_in[30], (const float*)d_in[31], Y, ystats);
    k_head<<<1, 128, 0, stream>>>(Y, ystats, (const float*)d_in[32], (const float*)d_in[33],
                                  (const float*)d_in[34], (const float*)d_in[35], (float*)d_out);
}

// Round 12
// 1528.536 us; speedup vs baseline: 1.0335x; 1.0335x over previous
//
#include <hip/hip_runtime.h>
#include <cstddef>

#define EPS 1e-5f
#define NNODE 30000
#define NEDGE 360000
#define NFEAT 92
#define EF 41
#define D 64
#define LAY 3
#define FCW 128
#define NG 64

typedef unsigned short bf16;
typedef __attribute__((ext_vector_type(8))) short short8v;   // 8 bf16 (4 VGPRs) — MFMA A/B frag
typedef __attribute__((ext_vector_type(4))) float float4v;   // MFMA C/D frag

__device__ __forceinline__ float b2f(bf16 u) { return __uint_as_float(((unsigned)u) << 16); }
__device__ __forceinline__ bf16 f2b(float f) {
    unsigned u = __float_as_uint(f);
    unsigned r = (u + 0x7FFFu + ((u >> 16) & 1u)) >> 16;
    return (bf16)r;
}
// fast native transcendentals (v_exp_f32 / v_log_f32 / v_rcp_f32): rel err ~1e-7.
__device__ __forceinline__ float fsp(float x) {       // softplus
    return fmaxf(x, 0.0f) + __logf(1.f + __expf(-fabsf(x)));
}
__device__ __forceinline__ float fsig(float x) {      // sigmoid
    return __builtin_amdgcn_rcpf(1.f + __expf(-x));
}
// packed (gate,scr) dword helpers: low u16 = gate, high u16 = scr
__device__ __forceinline__ float lof(unsigned u) { return __uint_as_float(u << 16); }
__device__ __forceinline__ float hif(unsigned u) { return __uint_as_float(u & 0xffff0000u); }

// ---------------- embedding matmul: pre = X[N,92] @ W[92,64] + b, accumulate col stats
#define EMB_RPB 64
__global__ __launch_bounds__(256) void k_emb_mm(const float* __restrict__ X, const float* __restrict__ W,
                                                const float* __restrict__ bias, float* __restrict__ pre,
                                                float* __restrict__ stats, int N) {
    __shared__ float xs[EMB_RPB][NFEAT];
    __shared__ float red[4][2][64];
    int tid = threadIdx.x;
    int lane = tid & 63, wid = tid >> 6;
    int r0 = blockIdx.x * EMB_RPB;
    float w[NFEAT];
#pragma unroll
    for (int k = 0; k < NFEAT; k++) w[k] = W[k * D + lane];
    float bcol = bias[lane];
    for (int i = tid; i < EMB_RPB * (NFEAT / 4); i += 256) {
        int rr = i / (NFEAT / 4), kk = i - rr * (NFEAT / 4);
        int r = r0 + rr;
        float4 v = (r < N) ? ((const float4*)(X + (size_t)r * NFEAT))[kk] : make_float4(0, 0, 0, 0);
        *(float4*)&xs[rr][kk * 4] = v;
    }
    __syncthreads();
    float s0 = 0.f, s1 = 0.f;
    for (int rr = wid * 16; rr < wid * 16 + 16; rr++) {
        int r = r0 + rr;
        if (r >= N) break;
        float acc = bcol;
#pragma unroll
        for (int k4 = 0; k4 < NFEAT; k4 += 4) {
            float4 xv = *(const float4*)&xs[rr][k4];
            acc += xv.x * w[k4] + xv.y * w[k4 + 1] + xv.z * w[k4 + 2] + xv.w * w[k4 + 3];
        }
        pre[r * D + lane] = acc;
        s0 += acc; s1 += acc * acc;
    }
    red[wid][0][lane] = s0; red[wid][1][lane] = s1;
    __syncthreads();
    if (tid < 64) {
        float a = red[0][0][lane] + red[1][0][lane] + red[2][0][lane] + red[3][0][lane];
        float b = red[0][1][lane] + red[1][1][lane] + red[2][1][lane] + red[3][1][lane];
        atomicAdd(&stats[lane], a);
        atomicAdd(&stats[64 + lane], b);
    }
}

// ---------------- BN + SiLU elementwise
__global__ void k_bnsilu(const float* __restrict__ pre, const float* __restrict__ stats,
                         const float* __restrict__ g, const float* __restrict__ beta,
                         float* __restrict__ h, int N, float invn) {
    int idx = blockIdx.x * blockDim.x + threadIdx.x;
    int total = N * D / 4;
    if (idx >= total) return;
    int c0 = (idx * 4) & 63;
    float4 p = ((const float4*)pre)[idx];
    float pv[4] = {p.x, p.y, p.z, p.w}, o[4];
#pragma unroll
    for (int t = 0; t < 4; t++) {
        int c = c0 + t;
        float m = stats[c] * invn;
        float v = stats[64 + c] * invn - m * m;
        float sc = g[c] * rsqrtf(fmaxf(v, 0.f) + EPS);
        float sh = beta[c] - m * sc;
        float y = sc * pv[t] + sh;
        o[t] = y * fsig(y);
    }
    ((float4*)h)[idx] = make_float4(o[0], o[1], o[2], o[3]);
}

// ---------------- pack edge weights: WT[layer][c][k] = bf16(W_ef[k][c]), c: 0..63 gate, 64..127 scr; k padded 41->64
__global__ void k_wpack(const float* __restrict__ convW, bf16* __restrict__ WT3) {
    int layer = blockIdx.x;
    const float* Wc = convW + (size_t)layer * 2 * 169 * 64;
    bf16* WT = WT3 + (size_t)layer * 128 * 64;
    for (int i = threadIdx.x; i < 128 * 64; i += blockDim.x) {
        int c = i >> 6, k = i & 63;
        float v = 0.f;
        if (k < EF) v = (c < 64) ? Wc[(128 + k) * 64 + c] : Wc[169 * 64 + (128 + k) * 64 + (c - 64)];
        WT[i] = f2b(v);
    }
}

// ---------------- CSR build: histogram -> block scan (deg -> cursor) -> fill (pos + DSTO)
__global__ void k_hist(const int* __restrict__ dst, int* __restrict__ deg, int E) {
    int i = blockIdx.x * blockDim.x + threadIdx.x;
    if (i < E) atomicAdd(&deg[dst[i]], 1);
}

__global__ __launch_bounds__(1024) void k_scan(int* __restrict__ deg, int N) {
    __shared__ int ls[1024];
    int tid = threadIdx.x;
    const int CH = (NNODE + 1023) / 1024;   // 30
    int base = tid * CH;
    int s = 0;
    for (int k = 0; k < CH; k++) {
        int i = base + k;
        if (i < N) s += deg[i];
    }
    ls[tid] = s;
    __syncthreads();
    for (int off = 1; off < 1024; off <<= 1) {
        int v = (tid >= off) ? ls[tid - off] : 0;
        __syncthreads();
        ls[tid] += v;
        __syncthreads();
    }
    int run = (tid == 0) ? 0 : ls[tid - 1];
    for (int k = 0; k < CH; k++) {
        int i = base + k;
        if (i < N) {
            int d = deg[i];
            deg[i] = run;        // exclusive prefix = fill cursor
            run += d;
        }
    }
}

__global__ void k_fill(const int* __restrict__ dst, int* __restrict__ cur, int* __restrict__ pos,
                       int* __restrict__ DSTO, int E) {
    int i = blockIdx.x * blockDim.x + threadIdx.x;
    if (i < E) {
        int p = atomicAdd(&cur[dst[i]], 1);
        pos[i] = p;
        DSTO[p] = dst[i];
    }
}

// ---------------- reorder (once per branch): coalesced ef read -> LDS bf16 stage -> FULL-LINE scatter
__global__ __launch_bounds__(256) void k_reord3(const float* __restrict__ ef, const int* __restrict__ src,
                                                const int* __restrict__ pos,
                                                bf16* __restrict__ EFR, int* __restrict__ SRCO, int E) {
    __shared__ bf16 stg[4][8][64];                     // 4 KB: 8 staged rows per wave
    int tid = threadIdx.x, lane = tid & 63, wid = tid >> 6;
    int e0 = (blockIdx.x * 4 + wid) * 8;               // wave's 8 edges (E % 32 == 0)
    if (e0 >= E) return;
    for (int i = lane; i < 512; i += 64) ((bf16*)stg[wid])[i] = 0;   // zero incl. k=41..63 pad
    __builtin_amdgcn_wave_barrier();
    const float* base = ef + (size_t)e0 * EF;
    for (int i = lane; i < 8 * EF; i += 64) {          // 328 dwords, coalesced
        float v = base[i];
        int r = i / EF, k = i - r * EF;
        stg[wid][r][k] = f2b(v);
    }
    __builtin_amdgcn_wave_barrier();
    int r = lane >> 3, sub = lane & 7;
    int p = pos[e0 + r];                               // 8 distinct, octet-broadcast
    uint4 val = *(const uint4*)&stg[wid][r][sub * 8];
    *(uint4*)(EFR + (size_t)p * 64 + sub * 8) = val;   // 8 lanes/row -> one full 128B line per row
    if (sub == 0) SRCO[p] = src[e0 + r];
}

// ---------------- node projections (MODE 1: fused h = softplus(BN(upd_prev)+h) applied in-place
// while staging). Packed output SRCP/DSTP; zeroes upd_cur for the subsequent apply pass.
#define NP_RPB 64
template <int MODE>
__global__ __launch_bounds__(256) void k_nodeproj(float* __restrict__ h, const float* __restrict__ Wc,
                                                  unsigned* __restrict__ SRCP, unsigned* __restrict__ DSTP,
                                                  const float* __restrict__ updp, const float* __restrict__ ustats,
                                                  const float* __restrict__ ng, const float* __restrict__ nb,
                                                  float* __restrict__ updz, int N, float invn) {
    __shared__ float hs[NP_RPB][D];
    int tid = threadIdx.x;
    for (int i = blockIdx.x * 256 + tid; i < N * D / 4; i += gridDim.x * 256)
        ((float4*)updz)[i] = make_float4(0.f, 0.f, 0.f, 0.f);
    // hoisted BN consts for fused updapply: kk = tid & 15 is loop-invariant -> 4 fixed cols
    float sc_[4], sh_[4];
    if (MODE) {
        int kk0 = tid & 15;
#pragma unroll
        for (int t = 0; t < 4; t++) {
            int c = kk0 * 4 + t;
            float m = ustats[c] * invn, v = ustats[64 + c] * invn - m * m;
            sc_[t] = ng[c] * rsqrtf(fmaxf(v, 0.f) + EPS);
            sh_[t] = nb[c] - m * sc_[t];
        }
    }
    int j = tid & 63;
    int mat = tid >> 6;          // 0: src-gate 1: src-scr 2: dst-gate 3: dst-scr
    int jj = mat & 1;
    int roff = (mat >> 1) * 64;
    const float* Wb = Wc + ((size_t)jj * 169 + roff) * 64 + j;
    float w[D];
#pragma unroll
    for (int k = 0; k < D; k++) w[k] = Wb[k * 64];
    int r0 = blockIdx.x * NP_RPB;
    for (int i = tid; i < NP_RPB * D / 4; i += 256) {
        int rr = i >> 4, kk = (i & 15);
        int r = r0 + rr;
        float4 v = make_float4(0, 0, 0, 0);
        if (r < N) {
            v = ((const float4*)(h + (size_t)r * D))[kk];
            if (MODE) {
                float4 u = ((const float4*)(updp + (size_t)r * D))[kk];
                float uv[4] = {u.x, u.y, u.z, u.w}, hv[4] = {v.x, v.y, v.z, v.w};
#pragma unroll
                for (int t = 0; t < 4; t++) hv[t] = fsp(sc_[t] * uv[t] + sh_[t] + hv[t]);
                v = make_float4(hv[0], hv[1], hv[2], hv[3]);
                ((float4*)(h + (size_t)r * D))[kk] = v;   // in-place; each element touched once
            }
        }
        *(float4*)&hs[rr][kk * 4] = v;
    }
    __syncthreads();
    unsigned short* out = (unsigned short*)((mat < 2) ? SRCP : DSTP);
    int rmax = min(NP_RPB, N - r0);
    for (int rr = 0; rr < rmax; rr++) {
        float acc = 0.f;
#pragma unroll
        for (int k4 = 0; k4 < D; k4 += 4) {
            float4 xv = *(const float4*)&hs[rr][k4];
            acc += xv.x * w[k4] + xv.y * w[k4 + 1] + xv.z * w[k4 + 2] + xv.w * w[k4 + 3];
        }
        out[(size_t)(r0 + rr) * 128 + j * 2 + jj] = f2b(acc);
    }
}

// ---------------- edge pass 1 (stats only): grid-stride over 16-edge tiles, register accumulation,
// per-block PLAIN-STORE partial. Dual LDS staging (R10-verified best variant).
#define ESTATS_BLOCKS 2048
__global__ __launch_bounds__(256) void k_estats(const bf16* __restrict__ EFR, const bf16* __restrict__ WT,
                                                const int* __restrict__ SRCO, const int* __restrict__ DSTO,
                                                const unsigned* __restrict__ SRCP, const unsigned* __restrict__ DSTP,
                                                float* __restrict__ PARTIAL) {
    __shared__ float red[4][4][64];
    __shared__ unsigned stg_[4][2][16][68];            // per-wave staged rows; stride 68 -> 2-way (free)
    int tid = threadIdx.x, lane = tid & 63, wid = tid >> 6;
    int lr = lane & 15, lg = lane >> 4;
    float stg[4], sqg[4], sts_[4], sqs[4];
#pragma unroll
    for (int t = 0; t < 4; t++) { stg[t] = 0.f; sqg[t] = 0.f; sts_[t] = 0.f; sqs[t] = 0.f; }
    int gw = blockIdx.x * 4 + wid, nw = gridDim.x * 4;
    const int NT = NEDGE / 16;                         // 22500 tiles
    for (int tile = gw; tile < NT; tile += nw) {
        int p0 = tile * 16;
        const bf16* arow = EFR + (size_t)(p0 + lr) * 64;   // 128B-aligned row
        short8v a0 = __builtin_nontemporal_load((const short8v*)(arow + lg * 8));
        short8v a1 = __builtin_nontemporal_load((const short8v*)(arow + 32 + lg * 8));  // k 41..63 zero
        int sidx[4], didx[4];
#pragma unroll
        for (int i = 0; i < 4; i++) {
            sidx[i] = SRCO[p0 + 4 * i + lg];
            didx[i] = DSTO[p0 + 4 * i + lg];           // dst-sorted: runs -> L1 hits
        }
        uint4 sv4[4], dv4[4];
#pragma unroll
        for (int i = 0; i < 4; i++) sv4[i] = ((const uint4*)(SRCP + (size_t)sidx[i] * 64))[lr];
#pragma unroll
        for (int i = 0; i < 4; i++) dv4[i] = ((const uint4*)(DSTP + (size_t)didx[i] * 64))[lr];
        __builtin_amdgcn_sched_barrier(0);
#pragma unroll
        for (int i = 0; i < 4; i++) {
            *(uint4*)&stg_[wid][0][4 * i + lg][4 * lr] = sv4[i];
            *(uint4*)&stg_[wid][1][4 * i + lg][4 * lr] = dv4[i];
        }
        __builtin_amdgcn_wave_barrier();
#pragma unroll
        for (int t = 0; t < 4; t++) {
            const bf16* wg = WT + (size_t)(16 * t + lr) * 64 + lg * 8;
            const bf16* wsc = WT + (size_t)(64 + 16 * t + lr) * 64 + lg * 8;
            float4v accg = {0.f, 0.f, 0.f, 0.f}, accs = {0.f, 0.f, 0.f, 0.f};
            accg = __builtin_amdgcn_mfma_f32_16x16x32_bf16(a0, *(const short8v*)wg, accg, 0, 0, 0);
            accg = __builtin_amdgcn_mfma_f32_16x16x32_bf16(a1, *(const short8v*)(wg + 32), accg, 0, 0, 0);
            accs = __builtin_amdgcn_mfma_f32_16x16x32_bf16(a0, *(const short8v*)wsc, accs, 0, 0, 0);
            accs = __builtin_amdgcn_mfma_f32_16x16x32_bf16(a1, *(const short8v*)(wsc + 32), accs, 0, 0, 0);
            int cl = 16 * t + lr;
#pragma unroll
            for (int j = 0; j < 4; j++) {
                int row = lg * 4 + j;                  // C/D: row = (lane>>4)*4 + reg, col = lane&15
                unsigned usv = stg_[wid][0][row][cl];
                unsigned udv = stg_[wid][1][row][cl];
                float pg = accg[j] + lof(usv) + lof(udv);
                float ps = accs[j] + hif(usv) + hif(udv);
                stg[t] += pg; sqg[t] += pg * pg; sts_[t] += ps; sqs[t] += ps * ps;
            }
        }
        __builtin_amdgcn_wave_barrier();               // LDS WAR fence before next-iter overwrite
    }
#pragma unroll
    for (int t = 0; t < 4; t++) {
        float v0 = stg[t], v1 = sqg[t], v2 = sts_[t], v3 = sqs[t];
        v0 += __shfl_xor(v0, 16); v0 += __shfl_xor(v0, 32);
        v1 += __shfl_xor(v1, 16); v1 += __shfl_xor(v1, 32);
        v2 += __shfl_xor(v2, 16); v2 += __shfl_xor(v2, 32);
        v3 += __shfl_xor(v3, 16); v3 += __shfl_xor(v3, 32);
        if (lg == 0) {
            red[wid][0][16 * t + lr] = v0; red[wid][1][16 * t + lr] = v1;
            red[wid][2][16 * t + lr] = v2; red[wid][3][16 * t + lr] = v3;
        }
    }
    __syncthreads();
    if (tid < 64) {
#pragma unroll
        for (int q = 0; q < 4; q++) {
            float v = red[0][q][lane] + red[1][q][lane] + red[2][q][lane] + red[3][q][lane];
            PARTIAL[(size_t)blockIdx.x * 256 + q * 64 + lane] = v;   // plain store, no hotspot
        }
    }
}

// ---------------- reduce per-block partials into stats (128 blocks x 16 unrolled coalesced rows)
#define RED_BLOCKS 128
__global__ __launch_bounds__(256) void k_redstats(const float* __restrict__ PARTIAL, float* __restrict__ stats) {
    int j = threadIdx.x;
    const int R = ESTATS_BLOCKS / RED_BLOCKS;          // 16
    const float* p = PARTIAL + (size_t)blockIdx.x * R * 256 + j;
    float s = 0.f;
#pragma unroll
    for (int k = 0; k < R; k++) s += p[(size_t)k * 256];
    atomicAdd(&stats[j], s);
}

// ---------------- edge pass 2 (recompute + apply + dst-run segmented scatter), grid-stride tiles.
// Dual LDS staging (R10-verified best variant).
__global__ __launch_bounds__(256) void k_eapply2(const bf16* __restrict__ EFR, const bf16* __restrict__ WT,
                                                 const int* __restrict__ SRCO, const int* __restrict__ DSTO,
                                                 const unsigned* __restrict__ SRCP, const unsigned* __restrict__ DSTP,
                                                 const float* __restrict__ stats,
                                                 const float* __restrict__ gg, const float* __restrict__ gb,
                                                 const float* __restrict__ sg, const float* __restrict__ sb,
                                                 float* __restrict__ upd) {
    __shared__ unsigned stg_[4][2][16][68];
    int tid = threadIdx.x, lane = tid & 63, wid = tid >> 6;
    int lr = lane & 15, lg = lane >> 4;
    // per-lane BN consts for cols 16t+lr (hoisted out of tile loop)
    float invE = 1.0f / (float)NEDGE;
    float scg[4], shg[4], scs[4], shs[4];
#pragma unroll
    for (int t = 0; t < 4; t++) {
        int col = 16 * t + lr;
        float m = stats[col] * invE;
        float v = stats[64 + col] * invE - m * m;
        scg[t] = gg[col] * rsqrtf(fmaxf(v, 0.f) + EPS);
        shg[t] = gb[col] - m * scg[t];
        m = stats[128 + col] * invE;
        v = stats[192 + col] * invE - m * m;
        scs[t] = sg[col] * rsqrtf(fmaxf(v, 0.f) + EPS);
        shs[t] = sb[col] - m * scs[t];
    }
    int gw = blockIdx.x * 4 + wid, nw = gridDim.x * 4;
    const int NT = NEDGE / 16;
    for (int tile = gw; tile < NT; tile += nw) {
        int p0 = tile * 16;
        const bf16* arow = EFR + (size_t)(p0 + lr) * 64;
        short8v a0 = __builtin_nontemporal_load((const short8v*)(arow + lg * 8));
        short8v a1 = __builtin_nontemporal_load((const short8v*)(arow + 32 + lg * 8));
        int sidx[4], didx[4];
#pragma unroll
        for (int i = 0; i < 4; i++) {
            sidx[i] = SRCO[p0 + 4 * i + lg];
            didx[i] = DSTO[p0 + 4 * i + lg];
        }
        uint4 sv4[4], dv4[4];
#pragma unroll
        for (int i = 0; i < 4; i++) sv4[i] = ((const uint4*)(SRCP + (size_t)sidx[i] * 64))[lr];
#pragma unroll
        for (int i = 0; i < 4; i++) dv4[i] = ((const uint4*)(DSTP + (size_t)didx[i] * 64))[lr];
        __builtin_amdgcn_sched_barrier(0);
#pragma unroll
        for (int i = 0; i < 4; i++) {
            *(uint4*)&stg_[wid][0][4 * i + lg][4 * lr] = sv4[i];
            *(uint4*)&stg_[wid][1][4 * i + lg][4 * lr] = dv4[i];
        }
        __builtin_amdgcn_wave_barrier();
        float acts[4][4];
#pragma unroll
        for (int t = 0; t < 4; t++) {
            const bf16* wg = WT + (size_t)(16 * t + lr) * 64 + lg * 8;
            const bf16* wsc = WT + (size_t)(64 + 16 * t + lr) * 64 + lg * 8;
            float4v accg = {0.f, 0.f, 0.f, 0.f}, accs = {0.f, 0.f, 0.f, 0.f};
            accg = __builtin_amdgcn_mfma_f32_16x16x32_bf16(a0, *(const short8v*)wg, accg, 0, 0, 0);
            accg = __builtin_amdgcn_mfma_f32_16x16x32_bf16(a1, *(const short8v*)(wg + 32), accg, 0, 0, 0);
            accs = __builtin_amdgcn_mfma_f32_16x16x32_bf16(a0, *(const short8v*)wsc, accs, 0, 0, 0);
            accs = __builtin_amdgcn_mfma_f32_16x16x32_bf16(a1, *(const short8v*)(wsc + 32), accs, 0, 0, 0);
            int cl = 16 * t + lr;
#pragma unroll
            for (int j = 0; j < 4; j++) {
                int row = lg * 4 + j;
                unsigned usv = stg_[wid][0][row][cl];
                unsigned udv = stg_[wid][1][row][cl];
                float pg = accg[j] + lof(usv) + lof(udv);
                float ps = accs[j] + hif(usv) + hif(udv);
                float yg = scg[t] * pg + shg[t], ys = scs[t] * ps + shs[t];
                acts[t][j] = fsp(ys) * fsig(yg);       // native exp/log/rcp
            }
        }
        // dst-run segmented reduction over the tile's 16 rows (dst-sorted -> few runs)
        int dval = DSTO[p0 + (lane & 15)];
        int prev = __shfl(dval, (lane == 0) ? 0 : lane - 1);
        unsigned long long bal = __ballot(lane < 16 && lane > 0 && dval != prev);
        unsigned mask = (unsigned)bal & 0xFFFFu;
        int a = 0;
        while (a < 16) {
            unsigned mm = mask & ~((2u << a) - 1);
            int b = mm ? __builtin_ctz(mm) : 16;
            int n = __shfl(dval, a);
#pragma unroll
            for (int t = 0; t < 4; t++) {
                float pp = 0.f;
#pragma unroll
                for (int j = 0; j < 4; j++) {
                    int row = lg * 4 + j;
                    if (row >= a && row < b) pp += acts[t][j];
                }
                pp += __shfl_xor(pp, 16);
                pp += __shfl_xor(pp, 32);
                if (lg == 0) atomicAdd(&upd[(size_t)n * 64 + 16 * t + lr], pp);
            }
            a = b;
        }
        __builtin_amdgcn_wave_barrier();               // LDS WAR fence before next-iter overwrite
    }
}

// ---------------- column stats of upd
__global__ __launch_bounds__(256) void k_colstats(const float* __restrict__ x, float* __restrict__ stats, int N) {
    int tid = threadIdx.x, lane = tid & 63, wid = tid >> 6;
    __shared__ float red[4][2][64];
    float s = 0, q = 0;
    int gw = blockIdx.x * 4 + wid, nw = gridDim.x * 4;
    for (int r = gw; r < N; r += nw) {
        float v = x[(size_t)r * D + lane];
        s += v; q += v * v;
    }
    red[wid][0][lane] = s; red[wid][1][lane] = q;
    __syncthreads();
    if (tid < 64) {
        float a = red[0][0][lane] + red[1][0][lane] + red[2][0][lane] + red[3][0][lane];
        float b = red[0][1][lane] + red[1][1][lane] + red[2][1][lane] + red[3][1][lane];
        atomicAdd(&stats[lane], a);
        atomicAdd(&stats[64 + lane], b);
    }
}

// ---------------- segment-sum pool (batch sorted); MODE 1 fuses final h = softplus(BN(upd)+h)
template <int MODE>
__global__ __launch_bounds__(256) void k_pool(const float* __restrict__ h, const int* __restrict__ batch,
                                              const float* __restrict__ upd, const float* __restrict__ ustats,
                                              const float* __restrict__ ng, const float* __restrict__ nb,
                                              float* __restrict__ pool, float* __restrict__ cnt, int N, float invn) {
    int tid = threadIdx.x, lane = tid & 63, wid = tid >> 6;
    float sc = 0.f, sh = 0.f;
    if (MODE) {
        float m = ustats[lane] * invn, v = ustats[64 + lane] * invn - m * m;
        sc = ng[lane] * rsqrtf(fmaxf(v, 0.f) + EPS);
        sh = nb[lane] - m * sc;
    }
    int w = blockIdx.x * 4 + wid, nw = gridDim.x * 4;
    int chunk = (N + nw - 1) / nw;
    int r0 = w * chunk, r1 = min(N, r0 + chunk);
    if (r0 >= r1) return;
    int cur = batch[r0];
    float acc = 0.f, c = 0.f;
    for (int r = r0; r < r1; r++) {
        int b = batch[r];
        if (b != cur) {
            atomicAdd(&pool[(size_t)cur * D + lane], acc);
            if (lane == 0) atomicAdd(&cnt[cur], c);
            acc = 0.f; c = 0.f; cur = b;
        }
        float hv = h[(size_t)r * D + lane];
        if (MODE) hv = fsp(sc * upd[(size_t)r * D + lane] + sh + hv);
        acc += hv;
        c += 1.f;
    }
    atomicAdd(&pool[(size_t)cur * D + lane], acc);
    if (lane == 0) atomicAdd(&cnt[cur], c);
}

// ---------------- fc
__global__ __launch_bounds__(128) void k_fc(const float* __restrict__ pool, const float* __restrict__ cnt,
                                            const float* __restrict__ fcW, const float* __restrict__ fcb,
                                            float* __restrict__ Y, float* __restrict__ ystats) {
    int g = blockIdx.x;
    int j = threadIdx.x;
    __shared__ float vt[FCW];
    {
        float s, c;
        if (j < 64) { s = pool[(size_t)g * D + j]; c = cnt[g]; }
        else { s = pool[4096 + (size_t)g * D + (j - 64)]; c = cnt[64 + g]; }
        vt[j] = s / fmaxf(c, 1.0f);
    }
    __syncthreads();
    float acc = fcb[j];
#pragma unroll
    for (int k4 = 0; k4 < FCW; k4 += 4) {
        float4 v = *(const float4*)&vt[k4];
        acc += v.x * fcW[(k4 + 0) * FCW + j] + v.y * fcW[(k4 + 1) * FCW + j] +
               v.z * fcW[(k4 + 2) * FCW + j] + v.w * fcW[(k4 + 3) * FCW + j];
    }
    Y[(size_t)g * FCW + j] = acc;
    atomicAdd(&ystats[j], acc);
    atomicAdd(&ystats[128 + j], acc * acc);
}

// ---------------- head
__global__ __launch_bounds__(128) void k_head(const float* __restrict__ Y, const float* __restrict__ ystats,
                                              const float* __restrict__ fg, const float* __restrict__ fb,
                                              const float* __restrict__ pW, const float* __restrict__ pb,
                                              float* __restrict__ out) {
    int j = threadIdx.x;
    __shared__ float ys[NG][FCW + 1];
    __shared__ float pw[FCW];
    float invn = 1.0f / (float)NG;
    float m = ystats[j] * invn, v = ystats[128 + j] * invn - m * m;
    float sc = fg[j] * rsqrtf(fmaxf(v, 0.f) + EPS);
    float sh = fb[j] - m * sc;
    for (int g = 0; g < NG; g++) {
        float y = sc * Y[(size_t)g * FCW + j] + sh;
        ys[g][j] = y * fsig(y);
    }
    pw[j] = pW[j];
    __syncthreads();
    if (j < NG) {
        float acc = pb[0];
        for (int k = 0; k < FCW; k++) acc += ys[j][k] * pw[k];
        out[j] = acc;
    }
}

// ---------------- workspace layout (bytes) — total ~92.2 MB <= granted 130,658,304
static const size_t OFF_EMBSTATS = 0;                    // [2][128] f32
static const size_t OFF_EDGESTATS = 1024;                // [6][256] f32
static const size_t OFF_UPDSTATS = 7168;                 // [6][128] f32
static const size_t OFF_POOL = 10240;                    // [2][4096] f32
static const size_t OFF_CNT = 43008;                     // [2][64] f32
static const size_t OFF_YSTATS = 43520;                  // [256] f32
static const size_t STATS_BYTES = 44544;
static const size_t OFF_H = 65536;                       // 7,680,000
static const size_t OFF_SCRATCH = OFF_H + 7680000;       // emb preact; then WT3/Y/DEG/POS/DSTO/PARTIAL
static const size_t OFF_UPD0 = OFF_SCRATCH + 7680000;    // ping-pong upd
static const size_t OFF_UPD1 = OFF_UPD0 + 7680000;
static const size_t OFF_SRCP = OFF_UPD1 + 7680000;       // uint [30000][64]
static const size_t OFF_DSTP = OFF_SRCP + 7680000;
static const size_t OFF_EFR = OFF_DSTP + 7680000;        // bf16 [360000][64] = 46,080,000 -> ends 92,225,536
// sub-layout of SCRATCH after bnsilu frees it:
static const size_t SC_WT3 = 0;          // 49152
static const size_t SC_Y = 49152;        // 32768
static const size_t SC_DEG = 81920;      // 120000
static const size_t SC_POS = 204800;     // 1,440,000
static const size_t SC_SRCO = 1644800;   // 1,440,000
static const size_t SC_DSTO = 3084800;   // 1,440,000
static const size_t SC_PART = 4524800;   // 2048*256*4 = 2,097,152 -> ends 6,621,952 < 7,680,000

extern "C" void kernel_launch(void* const* d_in, const int* in_sizes, int n_in,
                              void* d_out, int out_size, void* d_ws, size_t ws_size,
                              hipStream_t stream) {
    char* ws = (char*)d_ws;
    hipMemsetAsync(d_ws, 0, STATS_BYTES, stream);

    float* h = (float*)(ws + OFF_H);
    float* scratch = (float*)(ws + OFF_SCRATCH);
    bf16* WT3 = (bf16*)(ws + OFF_SCRATCH + SC_WT3);
    float* Y = (float*)(ws + OFF_SCRATCH + SC_Y);
    int* DEG = (int*)(ws + OFF_SCRATCH + SC_DEG);
    int* POS = (int*)(ws + OFF_SCRATCH + SC_POS);
    int* SRCO = (int*)(ws + OFF_SCRATCH + SC_SRCO);
    int* DSTO = (int*)(ws + OFF_SCRATCH + SC_DSTO);
    float* PARTIAL = (float*)(ws + OFF_SCRATCH + SC_PART);
    float* updbuf[2] = {(float*)(ws + OFF_UPD0), (float*)(ws + OFF_UPD1)};
    unsigned* SRCP = (unsigned*)(ws + OFF_SRCP);
    unsigned* DSTP = (unsigned*)(ws + OFF_DSTP);
    bf16* EFR = (bf16*)(ws + OFF_EFR);

    const int NPGRID = (NNODE + NP_RPB - 1) / NP_RPB;

    for (int br = 0; br < 2; br++) {
        const float* vf = (const float*)d_in[br ? 2 : 0];
        const float* ef = (const float*)d_in[br ? 3 : 1];
        const int* srci = (const int*)d_in[br ? 7 : 4];
        const int* dsti = (const int*)d_in[br ? 8 : 5];
        const int* bat = (const int*)d_in[br ? 9 : 6];
        const float* embW = (const float*)d_in[br ? 14 : 10];
        const float* embB = (const float*)d_in[br ? 15 : 11];
        const float* embG = (const float*)d_in[br ? 16 : 12];
        const float* embBe = (const float*)d_in[br ? 17 : 13];
        const float* convW = (const float*)d_in[br ? 24 : 18];
        const float* convG = (const float*)d_in[br ? 26 : 20];
        const float* convBe = (const float*)d_in[br ? 27 : 21];
        const float* convNG = (const float*)d_in[br ? 28 : 22];
        const float* convNB = (const float*)d_in[br ? 29 : 23];

        float* embstats = (float*)(ws + OFF_EMBSTATS) + br * 128;
        float* poolp = (float*)(ws + OFF_POOL) + br * 4096;
        float* cntp = (float*)(ws + OFF_CNT) + br * 64;

        k_emb_mm<<<(NNODE + EMB_RPB - 1) / EMB_RPB, 256, 0, stream>>>(vf, embW, embB, scratch, embstats, NNODE);
        k_bnsilu<<<NNODE * D / 4 / 256, 256, 0, stream>>>(scratch, embstats, embG, embBe, h, NNODE, 1.0f / NNODE);
        // scratch region now repurposed (rebuilt per branch)
        k_wpack<<<3, 256, 0, stream>>>(convW, WT3);
        hipMemsetAsync(DEG, 0, NNODE * 4, stream);
        k_hist<<<(NEDGE + 255) / 256, 256, 0, stream>>>(dsti, DEG, NEDGE);
        k_scan<<<1, 1024, 0, stream>>>(DEG, NNODE);
        k_fill<<<(NEDGE + 255) / 256, 256, 0, stream>>>(dsti, DEG, POS, DSTO, NEDGE);
        k_reord3<<<NEDGE / 32, 256, 0, stream>>>(ef, srci, POS, EFR, SRCO, NEDGE);

        for (int i = 0; i < LAY; i++) {
            const float* Wc = convW + (size_t)i * 2 * 169 * 64;
            const bf16* WT = WT3 + (size_t)i * 128 * 64;
            float* estats = (float*)(ws + OFF_EDGESTATS) + (br * 3 + i) * 256;
            float* ustats = (float*)(ws + OFF_UPDSTATS) + (br * 3 + i) * 128;
            const float* gg = convG + (i * 2 + 0) * 64;
            const float* gb = convBe + (i * 2 + 0) * 64;
            const float* sg = convG + (i * 2 + 1) * 64;
            const float* sb = convBe + (i * 2 + 1) * 64;
            float* updc = updbuf[i & 1];

            if (i == 0) {
                k_nodeproj<0><<<NPGRID, 256, 0, stream>>>(h, Wc, SRCP, DSTP, nullptr, nullptr, nullptr, nullptr,
                                                          updc, NNODE, 1.0f / NNODE);
            } else {
                float* ustatsp = (float*)(ws + OFF_UPDSTATS) + (br * 3 + i - 1) * 128;
                k_nodeproj<1><<<NPGRID, 256, 0, stream>>>(h, Wc, SRCP, DSTP, updbuf[(i - 1) & 1], ustatsp,
                                                          convNG + (i - 1) * 64, convNB + (i - 1) * 64,
                                                          updc, NNODE, 1.0f / NNODE);
            }
            k_estats<<<ESTATS_BLOCKS, 256, 0, stream>>>(EFR, WT, SRCO, DSTO, SRCP, DSTP, PARTIAL);
            k_redstats<<<RED_BLOCKS, 256, 0, stream>>>(PARTIAL, estats);
            k_eapply2<<<2048, 256, 0, stream>>>(EFR, WT, SRCO, DSTO, SRCP, DSTP, estats, gg, gb, sg, sb, updc);
            k_colstats<<<512, 256, 0, stream>>>(updc, ustats, NNODE);
        }
        {
            float* ustatsl = (float*)(ws + OFF_UPDSTATS) + (br * 3 + LAY - 1) * 128;
            k_pool<1><<<128, 256, 0, stream>>>(h, bat, updbuf[(LAY - 1) & 1], ustatsl,
                                               convNG + (LAY - 1) * 64, convNB + (LAY - 1) * 64,
                                               poolp, cntp, NNODE, 1.0f / NNODE);
        }
    }

    float* poolall = (float*)(ws + OFF_POOL);
    float* cntall = (float*)(ws + OFF_CNT);
    float* ystats = (float*)(ws + OFF_YSTATS);
    k_fc<<<64, 128, 0, stream>>>(poolall, cntall, (const float*)d_in[30], (const float*)d_in[31], Y, ystats);
    k_head<<<1, 128, 0, stream>>>(Y, ystats, (const float*)d_in[32], (const float*)d_in[33],
                                  (const float*)d_in[34], (const float*)d_in[35], (float*)d_out);
}

// Round 13
// 1397.811 us; speedup vs baseline: 1.1302x; 1.0935x over previous
//
#include <hip/hip_runtime.h>
#include <cstddef>

#define EPS 1e-5f
#define NNODE 30000
#define NEDGE 360000
#define NFEAT 92
#define EF 41
#define D 64
#define LAY 3
#define FCW 128
#define NG 64

typedef unsigned short bf16;
typedef __attribute__((ext_vector_type(8))) short short8v;   // 8 bf16 (4 VGPRs) — MFMA A/B frag
typedef __attribute__((ext_vector_type(4))) float float4v;   // MFMA C/D frag

__device__ __forceinline__ float b2f(bf16 u) { return __uint_as_float(((unsigned)u) << 16); }
__device__ __forceinline__ bf16 f2b(float f) {
    unsigned u = __float_as_uint(f);
    unsigned r = (u + 0x7FFFu + ((u >> 16) & 1u)) >> 16;
    return (bf16)r;
}
// fast native transcendentals (v_exp_f32 / v_log_f32 / v_rcp_f32): rel err ~1e-7.
__device__ __forceinline__ float fsp(float x) {       // softplus
    return fmaxf(x, 0.0f) + __logf(1.f + __expf(-fabsf(x)));
}
__device__ __forceinline__ float fsig(float x) {      // sigmoid
    return __builtin_amdgcn_rcpf(1.f + __expf(-x));
}
// packed (gate,scr) dword helpers: low u16 = gate, high u16 = scr
__device__ __forceinline__ float lof(unsigned u) { return __uint_as_float(u << 16); }
__device__ __forceinline__ float hif(unsigned u) { return __uint_as_float(u & 0xffff0000u); }

// ---------------- embedding matmul: pre = X[N,92] @ W[92,64] + b, accumulate col stats
#define EMB_RPB 64
__global__ __launch_bounds__(256) void k_emb_mm(const float* __restrict__ X, const float* __restrict__ W,
                                                const float* __restrict__ bias, float* __restrict__ pre,
                                                float* __restrict__ stats, int N) {
    __shared__ float xs[EMB_RPB][NFEAT];
    __shared__ float red[4][2][64];
    int tid = threadIdx.x;
    int lane = tid & 63, wid = tid >> 6;
    int r0 = blockIdx.x * EMB_RPB;
    float w[NFEAT];
#pragma unroll
    for (int k = 0; k < NFEAT; k++) w[k] = W[k * D + lane];
    float bcol = bias[lane];
    for (int i = tid; i < EMB_RPB * (NFEAT / 4); i += 256) {
        int rr = i / (NFEAT / 4), kk = i - rr * (NFEAT / 4);
        int r = r0 + rr;
        float4 v = (r < N) ? ((const float4*)(X + (size_t)r * NFEAT))[kk] : make_float4(0, 0, 0, 0);
        *(float4*)&xs[rr][kk * 4] = v;
    }
    __syncthreads();
    float s0 = 0.f, s1 = 0.f;
    for (int rr = wid * 16; rr < wid * 16 + 16; rr++) {
        int r = r0 + rr;
        if (r >= N) break;
        float acc = bcol;
#pragma unroll
        for (int k4 = 0; k4 < NFEAT; k4 += 4) {
            float4 xv = *(const float4*)&xs[rr][k4];
            acc += xv.x * w[k4] + xv.y * w[k4 + 1] + xv.z * w[k4 + 2] + xv.w * w[k4 + 3];
        }
        pre[r * D + lane] = acc;
        s0 += acc; s1 += acc * acc;
    }
    red[wid][0][lane] = s0; red[wid][1][lane] = s1;
    __syncthreads();
    if (tid < 64) {
        float a = red[0][0][lane] + red[1][0][lane] + red[2][0][lane] + red[3][0][lane];
        float b = red[0][1][lane] + red[1][1][lane] + red[2][1][lane] + red[3][1][lane];
        atomicAdd(&stats[lane], a);
        atomicAdd(&stats[64 + lane], b);
    }
}

// ---------------- BN + SiLU elementwise
__global__ void k_bnsilu(const float* __restrict__ pre, const float* __restrict__ stats,
                         const float* __restrict__ g, const float* __restrict__ beta,
                         float* __restrict__ h, int N, float invn) {
    int idx = blockIdx.x * blockDim.x + threadIdx.x;
    int total = N * D / 4;
    if (idx >= total) return;
    int c0 = (idx * 4) & 63;
    float4 p = ((const float4*)pre)[idx];
    float pv[4] = {p.x, p.y, p.z, p.w}, o[4];
#pragma unroll
    for (int t = 0; t < 4; t++) {
        int c = c0 + t;
        float m = stats[c] * invn;
        float v = stats[64 + c] * invn - m * m;
        float sc = g[c] * rsqrtf(fmaxf(v, 0.f) + EPS);
        float sh = beta[c] - m * sc;
        float y = sc * pv[t] + sh;
        o[t] = y * fsig(y);
    }
    ((float4*)h)[idx] = make_float4(o[0], o[1], o[2], o[3]);
}

// ---------------- pack edge weights WT[layer][c][k] AND node weights WN[layer][mat][c][k] (bf16)
__global__ void k_wpack(const float* __restrict__ convW, bf16* __restrict__ WT3, bf16* __restrict__ WN3) {
    int layer = blockIdx.x;
    const float* Wc = convW + (size_t)layer * 2 * 169 * 64;
    bf16* WT = WT3 + (size_t)layer * 128 * 64;
    for (int i = threadIdx.x; i < 128 * 64; i += blockDim.x) {
        int c = i >> 6, k = i & 63;
        float v = 0.f;
        if (k < EF) v = (c < 64) ? Wc[(128 + k) * 64 + c] : Wc[169 * 64 + (128 + k) * 64 + (c - 64)];
        WT[i] = f2b(v);
    }
    // WN[mat][c][k] = W[jj][(roff+k)][c], jj=mat&1 (gate/scr), roff=(mat>>1)*64 (src/dst)
    bf16* WN = WN3 + (size_t)layer * 4 * 64 * 64;
    for (int i = threadIdx.x; i < 4 * 64 * 64; i += blockDim.x) {
        int mat = i >> 12, c = (i >> 6) & 63, k = i & 63;
        int jj = mat & 1, roff = (mat >> 1) * 64;
        WN[i] = f2b(Wc[(size_t)jj * 169 * 64 + (roff + k) * 64 + c]);
    }
}

// ---------------- CSR build: histogram -> block scan (deg -> cursor) -> fill (pos + DSTO)
__global__ void k_hist(const int* __restrict__ dst, int* __restrict__ deg, int E) {
    int i = blockIdx.x * blockDim.x + threadIdx.x;
    if (i < E) atomicAdd(&deg[dst[i]], 1);
}

__global__ __launch_bounds__(1024) void k_scan(int* __restrict__ deg, int N) {
    __shared__ int ls[1024];
    int tid = threadIdx.x;
    const int CH = (NNODE + 1023) / 1024;   // 30
    int base = tid * CH;
    int s = 0;
    for (int k = 0; k < CH; k++) {
        int i = base + k;
        if (i < N) s += deg[i];
    }
    ls[tid] = s;
    __syncthreads();
    for (int off = 1; off < 1024; off <<= 1) {
        int v = (tid >= off) ? ls[tid - off] : 0;
        __syncthreads();
        ls[tid] += v;
        __syncthreads();
    }
    int run = (tid == 0) ? 0 : ls[tid - 1];
    for (int k = 0; k < CH; k++) {
        int i = base + k;
        if (i < N) {
            int d = deg[i];
            deg[i] = run;        // exclusive prefix = fill cursor
            run += d;
        }
    }
}

__global__ void k_fill(const int* __restrict__ dst, int* __restrict__ cur, int* __restrict__ pos,
                       int* __restrict__ DSTO, int E) {
    int i = blockIdx.x * blockDim.x + threadIdx.x;
    if (i < E) {
        int p = atomicAdd(&cur[dst[i]], 1);
        pos[i] = p;
        DSTO[p] = dst[i];
    }
}

// ---------------- reorder (once per branch): coalesced ef read -> LDS bf16 stage -> FULL-LINE scatter
__global__ __launch_bounds__(256) void k_reord3(const float* __restrict__ ef, const int* __restrict__ src,
                                                const int* __restrict__ pos,
                                                bf16* __restrict__ EFR, int* __restrict__ SRCO, int E) {
    __shared__ bf16 stg[4][8][64];                     // 4 KB: 8 staged rows per wave
    int tid = threadIdx.x, lane = tid & 63, wid = tid >> 6;
    int e0 = (blockIdx.x * 4 + wid) * 8;               // wave's 8 edges (E % 32 == 0)
    if (e0 >= E) return;
    for (int i = lane; i < 512; i += 64) ((bf16*)stg[wid])[i] = 0;   // zero incl. k=41..63 pad
    __builtin_amdgcn_wave_barrier();
    const float* base = ef + (size_t)e0 * EF;
    for (int i = lane; i < 8 * EF; i += 64) {          // 328 dwords, coalesced
        float v = base[i];
        int r = i / EF, k = i - r * EF;
        stg[wid][r][k] = f2b(v);
    }
    __builtin_amdgcn_wave_barrier();
    int r = lane >> 3, sub = lane & 7;
    int p = pos[e0 + r];                               // 8 distinct, octet-broadcast
    uint4 val = *(const uint4*)&stg[wid][r][sub * 8];
    *(uint4*)(EFR + (size_t)p * 64 + sub * 8) = val;   // 8 lanes/row -> one full 128B line per row
    if (sub == 0) SRCO[p] = src[e0 + r];
}

// ---------------- node projections via MFMA (h staged bf16 in LDS; wave w = mat w).
// MODE 1: fused h = softplus(BN(upd_prev)+h) applied in-place while staging. Zeroes upd_cur.
#define NP_RPB 64
template <int MODE>
__global__ __launch_bounds__(256) void k_nodeproj(float* __restrict__ h, const bf16* __restrict__ WN,
                                                  unsigned* __restrict__ SRCP, unsigned* __restrict__ DSTP,
                                                  const float* __restrict__ updp, const float* __restrict__ ustats,
                                                  const float* __restrict__ ng, const float* __restrict__ nb,
                                                  float* __restrict__ updz, int N, float invn) {
    __shared__ bf16 hs[NP_RPB][72];                    // pad 72: a-frag ds_read_b128 ~2-way (free)
    int tid = threadIdx.x;
    for (int i = blockIdx.x * 256 + tid; i < N * D / 4; i += gridDim.x * 256)
        ((float4*)updz)[i] = make_float4(0.f, 0.f, 0.f, 0.f);
    // hoisted BN consts for fused updapply: kk = tid & 15 loop-invariant -> 4 fixed cols
    float sc_[4], sh_[4];
    if (MODE) {
        int kk0 = tid & 15;
#pragma unroll
        for (int t = 0; t < 4; t++) {
            int c = kk0 * 4 + t;
            float m = ustats[c] * invn, v = ustats[64 + c] * invn - m * m;
            sc_[t] = ng[c] * rsqrtf(fmaxf(v, 0.f) + EPS);
            sh_[t] = nb[c] - m * sc_[t];
        }
    }
    int r0 = blockIdx.x * NP_RPB;
    // stage 64 rows of h as bf16 (apply fused updapply in f32 first)
    for (int i = tid; i < NP_RPB * D / 4; i += 256) {
        int rr = i >> 4, kk = (i & 15);
        int r = r0 + rr;
        float hv[4] = {0.f, 0.f, 0.f, 0.f};
        if (r < N) {
            float4 v = ((const float4*)(h + (size_t)r * D))[kk];
            hv[0] = v.x; hv[1] = v.y; hv[2] = v.z; hv[3] = v.w;
            if (MODE) {
                float4 u = ((const float4*)(updp + (size_t)r * D))[kk];
                float uv[4] = {u.x, u.y, u.z, u.w};
#pragma unroll
                for (int t = 0; t < 4; t++) hv[t] = fsp(sc_[t] * uv[t] + sh_[t] + hv[t]);
                ((float4*)(h + (size_t)r * D))[kk] = make_float4(hv[0], hv[1], hv[2], hv[3]);
            }
        }
#pragma unroll
        for (int t = 0; t < 4; t++) hs[rr][kk * 4 + t] = f2b(hv[t]);
    }
    __syncthreads();
    int lane = tid & 63, mat = tid >> 6;               // wave = mat (0: src-gate 1: src-scr 2: dst-gate 3: dst-scr)
    int lr = lane & 15, lg = lane >> 4;
    int jj = mat & 1;
    // hoist all 8 B-frags for this mat: WN[mat][c=ct*16+lr][kh*32 + lg*8 + i]
    const bf16* WNm = WN + (size_t)mat * 64 * 64;
    short8v bfr[4][2];
#pragma unroll
    for (int ct = 0; ct < 4; ct++)
#pragma unroll
        for (int kh = 0; kh < 2; kh++)
            bfr[ct][kh] = *(const short8v*)(WNm + (size_t)(ct * 16 + lr) * 64 + kh * 32 + lg * 8);
    unsigned short* out = (unsigned short*)((mat < 2) ? SRCP : DSTP);
#pragma unroll
    for (int rt = 0; rt < 4; rt++) {
        short8v a0 = *(const short8v*)&hs[rt * 16 + lr][lg * 8];        // A[lr][k 0..31]
        short8v a1 = *(const short8v*)&hs[rt * 16 + lr][32 + lg * 8];   // A[lr][k 32..63]
        float4v acc[4];
#pragma unroll
        for (int ct = 0; ct < 4; ct++) {
            float4v a_ = {0.f, 0.f, 0.f, 0.f};
            a_ = __builtin_amdgcn_mfma_f32_16x16x32_bf16(a0, bfr[ct][0], a_, 0, 0, 0);
            a_ = __builtin_amdgcn_mfma_f32_16x16x32_bf16(a1, bfr[ct][1], a_, 0, 0, 0);
            acc[ct] = a_;
        }
#pragma unroll
        for (int ct = 0; ct < 4; ct++) {
            int col = ct * 16 + lr;
#pragma unroll
            for (int j = 0; j < 4; j++) {
                int row = r0 + rt * 16 + lg * 4 + j;   // C/D: row = (lane>>4)*4 + reg, col = lane&15
                if (row < N) out[(size_t)row * 128 + col * 2 + jj] = f2b(acc[ct][j]);
            }
        }
    }
}

// ---------------- edge pass 1 (stats only): grid-stride over 16-edge tiles, register accumulation,
// per-block PLAIN-STORE partial. Dual LDS staging (R10-verified best variant).
#define ESTATS_BLOCKS 2048
__global__ __launch_bounds__(256) void k_estats(const bf16* __restrict__ EFR, const bf16* __restrict__ WT,
                                                const int* __restrict__ SRCO, const int* __restrict__ DSTO,
                                                const unsigned* __restrict__ SRCP, const unsigned* __restrict__ DSTP,
                                                float* __restrict__ PARTIAL) {
    __shared__ float red[4][4][64];
    __shared__ unsigned stg_[4][2][16][68];            // per-wave staged rows; stride 68 -> 2-way (free)
    int tid = threadIdx.x, lane = tid & 63, wid = tid >> 6;
    int lr = lane & 15, lg = lane >> 4;
    float stg[4], sqg[4], sts_[4], sqs[4];
#pragma unroll
    for (int t = 0; t < 4; t++) { stg[t] = 0.f; sqg[t] = 0.f; sts_[t] = 0.f; sqs[t] = 0.f; }
    int gw = blockIdx.x * 4 + wid, nw = gridDim.x * 4;
    const int NT = NEDGE / 16;                         // 22500 tiles
    for (int tile = gw; tile < NT; tile += nw) {
        int p0 = tile * 16;
        const bf16* arow = EFR + (size_t)(p0 + lr) * 64;   // 128B-aligned row
        short8v a0 = __builtin_nontemporal_load((const short8v*)(arow + lg * 8));
        short8v a1 = __builtin_nontemporal_load((const short8v*)(arow + 32 + lg * 8));  // k 41..63 zero
        int sidx[4], didx[4];
#pragma unroll
        for (int i = 0; i < 4; i++) {
            sidx[i] = SRCO[p0 + 4 * i + lg];
            didx[i] = DSTO[p0 + 4 * i + lg];           // dst-sorted: runs -> L1 hits
        }
        uint4 sv4[4], dv4[4];
#pragma unroll
        for (int i = 0; i < 4; i++) sv4[i] = ((const uint4*)(SRCP + (size_t)sidx[i] * 64))[lr];
#pragma unroll
        for (int i = 0; i < 4; i++) dv4[i] = ((const uint4*)(DSTP + (size_t)didx[i] * 64))[lr];
        __builtin_amdgcn_sched_barrier(0);
#pragma unroll
        for (int i = 0; i < 4; i++) {
            *(uint4*)&stg_[wid][0][4 * i + lg][4 * lr] = sv4[i];
            *(uint4*)&stg_[wid][1][4 * i + lg][4 * lr] = dv4[i];
        }
        __builtin_amdgcn_wave_barrier();
#pragma unroll
        for (int t = 0; t < 4; t++) {
            const bf16* wg = WT + (size_t)(16 * t + lr) * 64 + lg * 8;
            const bf16* wsc = WT + (size_t)(64 + 16 * t + lr) * 64 + lg * 8;
            float4v accg = {0.f, 0.f, 0.f, 0.f}, accs = {0.f, 0.f, 0.f, 0.f};
            accg = __builtin_amdgcn_mfma_f32_16x16x32_bf16(a0, *(const short8v*)wg, accg, 0, 0, 0);
            accg = __builtin_amdgcn_mfma_f32_16x16x32_bf16(a1, *(const short8v*)(wg + 32), accg, 0, 0, 0);
            accs = __builtin_amdgcn_mfma_f32_16x16x32_bf16(a0, *(const short8v*)wsc, accs, 0, 0, 0);
            accs = __builtin_amdgcn_mfma_f32_16x16x32_bf16(a1, *(const short8v*)(wsc + 32), accs, 0, 0, 0);
            int cl = 16 * t + lr;
#pragma unroll
            for (int j = 0; j < 4; j++) {
                int row = lg * 4 + j;                  // C/D: row = (lane>>4)*4 + reg, col = lane&15
                unsigned usv = stg_[wid][0][row][cl];
                unsigned udv = stg_[wid][1][row][cl];
                float pg = accg[j] + lof(usv) + lof(udv);
                float ps = accs[j] + hif(usv) + hif(udv);
                stg[t] += pg; sqg[t] += pg * pg; sts_[t] += ps; sqs[t] += ps * ps;
            }
        }
        __builtin_amdgcn_wave_barrier();               // LDS WAR fence before next-iter overwrite
    }
#pragma unroll
    for (int t = 0; t < 4; t++) {
        float v0 = stg[t], v1 = sqg[t], v2 = sts_[t], v3 = sqs[t];
        v0 += __shfl_xor(v0, 16); v0 += __shfl_xor(v0, 32);
        v1 += __shfl_xor(v1, 16); v1 += __shfl_xor(v1, 32);
        v2 += __shfl_xor(v2, 16); v2 += __shfl_xor(v2, 32);
        v3 += __shfl_xor(v3, 16); v3 += __shfl_xor(v3, 32);
        if (lg == 0) {
            red[wid][0][16 * t + lr] = v0; red[wid][1][16 * t + lr] = v1;
            red[wid][2][16 * t + lr] = v2; red[wid][3][16 * t + lr] = v3;
        }
    }
    __syncthreads();
    if (tid < 64) {
#pragma unroll
        for (int q = 0; q < 4; q++) {
            float v = red[0][q][lane] + red[1][q][lane] + red[2][q][lane] + red[3][q][lane];
            PARTIAL[(size_t)blockIdx.x * 256 + q * 64 + lane] = v;   // plain store, no hotspot
        }
    }
}

// ---------------- reduce per-block partials into stats (128 blocks x 16 unrolled coalesced rows)
#define RED_BLOCKS 128
__global__ __launch_bounds__(256) void k_redstats(const float* __restrict__ PARTIAL, float* __restrict__ stats) {
    int j = threadIdx.x;
    const int R = ESTATS_BLOCKS / RED_BLOCKS;          // 16
    const float* p = PARTIAL + (size_t)blockIdx.x * R * 256 + j;
    float s = 0.f;
#pragma unroll
    for (int k = 0; k < R; k++) s += p[(size_t)k * 256];
    atomicAdd(&stats[j], s);
}

// ---------------- edge pass 2 (recompute + apply + dst-run segmented scatter), grid-stride tiles.
// Dual LDS staging (R10-verified best variant).
__global__ __launch_bounds__(256) void k_eapply2(const bf16* __restrict__ EFR, const bf16* __restrict__ WT,
                                                 const int* __restrict__ SRCO, const int* __restrict__ DSTO,
                                                 const unsigned* __restrict__ SRCP, const unsigned* __restrict__ DSTP,
                                                 const float* __restrict__ stats,
                                                 const float* __restrict__ gg, const float* __restrict__ gb,
                                                 const float* __restrict__ sg, const float* __restrict__ sb,
                                                 float* __restrict__ upd) {
    __shared__ unsigned stg_[4][2][16][68];
    int tid = threadIdx.x, lane = tid & 63, wid = tid >> 6;
    int lr = lane & 15, lg = lane >> 4;
    // per-lane BN consts for cols 16t+lr (hoisted out of tile loop)
    float invE = 1.0f / (float)NEDGE;
    float scg[4], shg[4], scs[4], shs[4];
#pragma unroll
    for (int t = 0; t < 4; t++) {
        int col = 16 * t + lr;
        float m = stats[col] * invE;
        float v = stats[64 + col] * invE - m * m;
        scg[t] = gg[col] * rsqrtf(fmaxf(v, 0.f) + EPS);
        shg[t] = gb[col] - m * scg[t];
        m = stats[128 + col] * invE;
        v = stats[192 + col] * invE - m * m;
        scs[t] = sg[col] * rsqrtf(fmaxf(v, 0.f) + EPS);
        shs[t] = sb[col] - m * scs[t];
    }
    int gw = blockIdx.x * 4 + wid, nw = gridDim.x * 4;
    const int NT = NEDGE / 16;
    for (int tile = gw; tile < NT; tile += nw) {
        int p0 = tile * 16;
        const bf16* arow = EFR + (size_t)(p0 + lr) * 64;
        short8v a0 = __builtin_nontemporal_load((const short8v*)(arow + lg * 8));
        short8v a1 = __builtin_nontemporal_load((const short8v*)(arow + 32 + lg * 8));
        int sidx[4], didx[4];
#pragma unroll
        for (int i = 0; i < 4; i++) {
            sidx[i] = SRCO[p0 + 4 * i + lg];
            didx[i] = DSTO[p0 + 4 * i + lg];
        }
        uint4 sv4[4], dv4[4];
#pragma unroll
        for (int i = 0; i < 4; i++) sv4[i] = ((const uint4*)(SRCP + (size_t)sidx[i] * 64))[lr];
#pragma unroll
        for (int i = 0; i < 4; i++) dv4[i] = ((const uint4*)(DSTP + (size_t)didx[i] * 64))[lr];
        __builtin_amdgcn_sched_barrier(0);
#pragma unroll
        for (int i = 0; i < 4; i++) {
            *(uint4*)&stg_[wid][0][4 * i + lg][4 * lr] = sv4[i];
            *(uint4*)&stg_[wid][1][4 * i + lg][4 * lr] = dv4[i];
        }
        __builtin_amdgcn_wave_barrier();
        float acts[4][4];
#pragma unroll
        for (int t = 0; t < 4; t++) {
            const bf16* wg = WT + (size_t)(16 * t + lr) * 64 + lg * 8;
            const bf16* wsc = WT + (size_t)(64 + 16 * t + lr) * 64 + lg * 8;
            float4v accg = {0.f, 0.f, 0.f, 0.f}, accs = {0.f, 0.f, 0.f, 0.f};
            accg = __builtin_amdgcn_mfma_f32_16x16x32_bf16(a0, *(const short8v*)wg, accg, 0, 0, 0);
            accg = __builtin_amdgcn_mfma_f32_16x16x32_bf16(a1, *(const short8v*)(wg + 32), accg, 0, 0, 0);
            accs = __builtin_amdgcn_mfma_f32_16x16x32_bf16(a0, *(const short8v*)wsc, accs, 0, 0, 0);
            accs = __builtin_amdgcn_mfma_f32_16x16x32_bf16(a1, *(const short8v*)(wsc + 32), accs, 0, 0, 0);
            int cl = 16 * t + lr;
#pragma unroll
            for (int j = 0; j < 4; j++) {
                int row = lg * 4 + j;
                unsigned usv = stg_[wid][0][row][cl];
                unsigned udv = stg_[wid][1][row][cl];
                float pg = accg[j] + lof(usv) + lof(udv);
                float ps = accs[j] + hif(usv) + hif(udv);
                float yg = scg[t] * pg + shg[t], ys = scs[t] * ps + shs[t];
                acts[t][j] = fsp(ys) * fsig(yg);       // native exp/log/rcp
            }
        }
        // dst-run segmented reduction over the tile's 16 rows (dst-sorted -> few runs)
        int dval = DSTO[p0 + (lane & 15)];
        int prev = __shfl(dval, (lane == 0) ? 0 : lane - 1);
        unsigned long long bal = __ballot(lane < 16 && lane > 0 && dval != prev);
        unsigned mask = (unsigned)bal & 0xFFFFu;
        int a = 0;
        while (a < 16) {
            unsigned mm = mask & ~((2u << a) - 1);
            int b = mm ? __builtin_ctz(mm) : 16;
            int n = __shfl(dval, a);
#pragma unroll
            for (int t = 0; t < 4; t++) {
                float pp = 0.f;
#pragma unroll
                for (int j = 0; j < 4; j++) {
                    int row = lg * 4 + j;
                    if (row >= a && row < b) pp += acts[t][j];
                }
                pp += __shfl_xor(pp, 16);
                pp += __shfl_xor(pp, 32);
                if (lg == 0) atomicAdd(&upd[(size_t)n * 64 + 16 * t + lr], pp);
            }
            a = b;
        }
        __builtin_amdgcn_wave_barrier();               // LDS WAR fence before next-iter overwrite
    }
}

// ---------------- column stats of upd
__global__ __launch_bounds__(256) void k_colstats(const float* __restrict__ x, float* __restrict__ stats, int N) {
    int tid = threadIdx.x, lane = tid & 63, wid = tid >> 6;
    __shared__ float red[4][2][64];
    float s = 0, q = 0;
    int gw = blockIdx.x * 4 + wid, nw = gridDim.x * 4;
    for (int r = gw; r < N; r += nw) {
        float v = x[(size_t)r * D + lane];
        s += v; q += v * v;
    }
    red[wid][0][lane] = s; red[wid][1][lane] = q;
    __syncthreads();
    if (tid < 64) {
        float a = red[0][0][lane] + red[1][0][lane] + red[2][0][lane] + red[3][0][lane];
        float b = red[0][1][lane] + red[1][1][lane] + red[2][1][lane] + red[3][1][lane];
        atomicAdd(&stats[lane], a);
        atomicAdd(&stats[64 + lane], b);
    }
}

// ---------------- segment-sum pool (batch sorted); MODE 1 fuses final h = softplus(BN(upd)+h)
template <int MODE>
__global__ __launch_bounds__(256) void k_pool(const float* __restrict__ h, const int* __restrict__ batch,
                                              const float* __restrict__ upd, const float* __restrict__ ustats,
                                              const float* __restrict__ ng, const float* __restrict__ nb,
                                              float* __restrict__ pool, float* __restrict__ cnt, int N, float invn) {
    int tid = threadIdx.x, lane = tid & 63, wid = tid >> 6;
    float sc = 0.f, sh = 0.f;
    if (MODE) {
        float m = ustats[lane] * invn, v = ustats[64 + lane] * invn - m * m;
        sc = ng[lane] * rsqrtf(fmaxf(v, 0.f) + EPS);
        sh = nb[lane] - m * sc;
    }
    int w = blockIdx.x * 4 + wid, nw = gridDim.x * 4;
    int chunk = (N + nw - 1) / nw;
    int r0 = w * chunk, r1 = min(N, r0 + chunk);
    if (r0 >= r1) return;
    int cur = batch[r0];
    float acc = 0.f, c = 0.f;
    for (int r = r0; r < r1; r++) {
        int b = batch[r];
        if (b != cur) {
            atomicAdd(&pool[(size_t)cur * D + lane], acc);
            if (lane == 0) atomicAdd(&cnt[cur], c);
            acc = 0.f; c = 0.f; cur = b;
        }
        float hv = h[(size_t)r * D + lane];
        if (MODE) hv = fsp(sc * upd[(size_t)r * D + lane] + sh + hv);
        acc += hv;
        c += 1.f;
    }
    atomicAdd(&pool[(size_t)cur * D + lane], acc);
    if (lane == 0) atomicAdd(&cnt[cur], c);
}

// ---------------- fc
__global__ __launch_bounds__(128) void k_fc(const float* __restrict__ pool, const float* __restrict__ cnt,
                                            const float* __restrict__ fcW, const float* __restrict__ fcb,
                                            float* __restrict__ Y, float* __restrict__ ystats) {
    int g = blockIdx.x;
    int j = threadIdx.x;
    __shared__ float vt[FCW];
    {
        float s, c;
        if (j < 64) { s = pool[(size_t)g * D + j]; c = cnt[g]; }
        else { s = pool[4096 + (size_t)g * D + (j - 64)]; c = cnt[64 + g]; }
        vt[j] = s / fmaxf(c, 1.0f);
    }
    __syncthreads();
    float acc = fcb[j];
#pragma unroll
    for (int k4 = 0; k4 < FCW; k4 += 4) {
        float4 v = *(const float4*)&vt[k4];
        acc += v.x * fcW[(k4 + 0) * FCW + j] + v.y * fcW[(k4 + 1) * FCW + j] +
               v.z * fcW[(k4 + 2) * FCW + j] + v.w * fcW[(k4 + 3) * FCW + j];
    }
    Y[(size_t)g * FCW + j] = acc;
    atomicAdd(&ystats[j], acc);
    atomicAdd(&ystats[128 + j], acc * acc);
}

// ---------------- head
__global__ __launch_bounds__(128) void k_head(const float* __restrict__ Y, const float* __restrict__ ystats,
                                              const float* __restrict__ fg, const float* __restrict__ fb,
                                              const float* __restrict__ pW, const float* __restrict__ pb,
                                              float* __restrict__ out) {
    int j = threadIdx.x;
    __shared__ float ys[NG][FCW + 1];
    __shared__ float pw[FCW];
    float invn = 1.0f / (float)NG;
    float m = ystats[j] * invn, v = ystats[128 + j] * invn - m * m;
    float sc = fg[j] * rsqrtf(fmaxf(v, 0.f) + EPS);
    float sh = fb[j] - m * sc;
    for (int g = 0; g < NG; g++) {
        float y = sc * Y[(size_t)g * FCW + j] + sh;
        ys[g][j] = y * fsig(y);
    }
    pw[j] = pW[j];
    __syncthreads();
    if (j < NG) {
        float acc = pb[0];
        for (int k = 0; k < FCW; k++) acc += ys[j][k] * pw[k];
        out[j] = acc;
    }
}

// ---------------- workspace layout (bytes) — total ~92.2 MB <= granted 130,658,304
static const size_t OFF_EMBSTATS = 0;                    // [2][128] f32
static const size_t OFF_EDGESTATS = 1024;                // [6][256] f32
static const size_t OFF_UPDSTATS = 7168;                 // [6][128] f32
static const size_t OFF_POOL = 10240;                    // [2][4096] f32
static const size_t OFF_CNT = 43008;                     // [2][64] f32
static const size_t OFF_YSTATS = 43520;                  // [256] f32
static const size_t STATS_BYTES = 44544;
static const size_t OFF_H = 65536;                       // 7,680,000
static const size_t OFF_SCRATCH = OFF_H + 7680000;       // emb preact; then WT3/WN3/Y/DEG/POS/DSTO/PARTIAL
static const size_t OFF_UPD0 = OFF_SCRATCH + 7680000;    // ping-pong upd
static const size_t OFF_UPD1 = OFF_UPD0 + 7680000;
static const size_t OFF_SRCP = OFF_UPD1 + 7680000;       // uint [30000][64]
static const size_t OFF_DSTP = OFF_SRCP + 7680000;
static const size_t OFF_EFR = OFF_DSTP + 7680000;        // bf16 [360000][64] = 46,080,000 -> ends 92,225,536
// sub-layout of SCRATCH after bnsilu frees it:
static const size_t SC_WT3 = 0;          // 49152
static const size_t SC_Y = 49152;        // 32768
static const size_t SC_DEG = 81920;      // 120000
static const size_t SC_POS = 204800;     // 1,440,000
static const size_t SC_SRCO = 1644800;   // 1,440,000
static const size_t SC_DSTO = 3084800;   // 1,440,000
static const size_t SC_PART = 4524800;   // 2048*256*4 = 2,097,152
static const size_t SC_WN3 = 6621952;    // 3*4*64*64*2 = 98,304 -> ends 6,720,256 < 7,680,000

extern "C" void kernel_launch(void* const* d_in, const int* in_sizes, int n_in,
                              void* d_out, int out_size, void* d_ws, size_t ws_size,
                              hipStream_t stream) {
    char* ws = (char*)d_ws;
    hipMemsetAsync(d_ws, 0, STATS_BYTES, stream);

    float* h = (float*)(ws + OFF_H);
    float* scratch = (float*)(ws + OFF_SCRATCH);
    bf16* WT3 = (bf16*)(ws + OFF_SCRATCH + SC_WT3);
    bf16* WN3 = (bf16*)(ws + OFF_SCRATCH + SC_WN3);
    float* Y = (float*)(ws + OFF_SCRATCH + SC_Y);
    int* DEG = (int*)(ws + OFF_SCRATCH + SC_DEG);
    int* POS = (int*)(ws + OFF_SCRATCH + SC_POS);
    int* SRCO = (int*)(ws + OFF_SCRATCH + SC_SRCO);
    int* DSTO = (int*)(ws + OFF_SCRATCH + SC_DSTO);
    float* PARTIAL = (float*)(ws + OFF_SCRATCH + SC_PART);
    float* updbuf[2] = {(float*)(ws + OFF_UPD0), (float*)(ws + OFF_UPD1)};
    unsigned* SRCP = (unsigned*)(ws + OFF_SRCP);
    unsigned* DSTP = (unsigned*)(ws + OFF_DSTP);
    bf16* EFR = (bf16*)(ws + OFF_EFR);

    const int NPGRID = (NNODE + NP_RPB - 1) / NP_RPB;

    for (int br = 0; br < 2; br++) {
        const float* vf = (const float*)d_in[br ? 2 : 0];
        const float* ef = (const float*)d_in[br ? 3 : 1];
        const int* srci = (const int*)d_in[br ? 7 : 4];
        const int* dsti = (const int*)d_in[br ? 8 : 5];
        const int* bat = (const int*)d_in[br ? 9 : 6];
        const float* embW = (const float*)d_in[br ? 14 : 10];
        const float* embB = (const float*)d_in[br ? 15 : 11];
        const float* embG = (const float*)d_in[br ? 16 : 12];
        const float* embBe = (const float*)d_in[br ? 17 : 13];
        const float* convW = (const float*)d_in[br ? 24 : 18];
        const float* convG = (const float*)d_in[br ? 26 : 20];
        const float* convBe = (const float*)d_in[br ? 27 : 21];
        const float* convNG = (const float*)d_in[br ? 28 : 22];
        const float* convNB = (const float*)d_in[br ? 29 : 23];

        float* embstats = (float*)(ws + OFF_EMBSTATS) + br * 128;
        float* poolp = (float*)(ws + OFF_POOL) + br * 4096;
        float* cntp = (float*)(ws + OFF_CNT) + br * 64;

        k_emb_mm<<<(NNODE + EMB_RPB - 1) / EMB_RPB, 256, 0, stream>>>(vf, embW, embB, scratch, embstats, NNODE);
        k_bnsilu<<<NNODE * D / 4 / 256, 256, 0, stream>>>(scratch, embstats, embG, embBe, h, NNODE, 1.0f / NNODE);
        // scratch region now repurposed (rebuilt per branch)
        k_wpack<<<3, 256, 0, stream>>>(convW, WT3, WN3);
        hipMemsetAsync(DEG, 0, NNODE * 4, stream);
        k_hist<<<(NEDGE + 255) / 256, 256, 0, stream>>>(dsti, DEG, NEDGE);
        k_scan<<<1, 1024, 0, stream>>>(DEG, NNODE);
        k_fill<<<(NEDGE + 255) / 256, 256, 0, stream>>>(dsti, DEG, POS, DSTO, NEDGE);
        k_reord3<<<NEDGE / 32, 256, 0, stream>>>(ef, srci, POS, EFR, SRCO, NEDGE);

        for (int i = 0; i < LAY; i++) {
            const bf16* WT = WT3 + (size_t)i * 128 * 64;
            const bf16* WN = WN3 + (size_t)i * 4 * 64 * 64;
            float* estats = (float*)(ws + OFF_EDGESTATS) + (br * 3 + i) * 256;
            float* ustats = (float*)(ws + OFF_UPDSTATS) + (br * 3 + i) * 128;
            const float* gg = convG + (i * 2 + 0) * 64;
            const float* gb = convBe + (i * 2 + 0) * 64;
            const float* sg = convG + (i * 2 + 1) * 64;
            const float* sb = convBe + (i * 2 + 1) * 64;
            float* updc = updbuf[i & 1];

            if (i == 0) {
                k_nodeproj<0><<<NPGRID, 256, 0, stream>>>(h, WN, SRCP, DSTP, nullptr, nullptr, nullptr, nullptr,
                                                          updc, NNODE, 1.0f / NNODE);
            } else {
                float* ustatsp = (float*)(ws + OFF_UPDSTATS) + (br * 3 + i - 1) * 128;
                k_nodeproj<1><<<NPGRID, 256, 0, stream>>>(h, WN, SRCP, DSTP, updbuf[(i - 1) & 1], ustatsp,
                                                          convNG + (i - 1) * 64, convNB + (i - 1) * 64,
                                                          updc, NNODE, 1.0f / NNODE);
            }
            k_estats<<<ESTATS_BLOCKS, 256, 0, stream>>>(EFR, WT, SRCO, DSTO, SRCP, DSTP, PARTIAL);
            k_redstats<<<RED_BLOCKS, 256, 0, stream>>>(PARTIAL, estats);
            k_eapply2<<<2048, 256, 0, stream>>>(EFR, WT, SRCO, DSTO, SRCP, DSTP, estats, gg, gb, sg, sb, updc);
            k_colstats<<<512, 256, 0, stream>>>(updc, ustats, NNODE);
        }
        {
            float* ustatsl = (float*)(ws + OFF_UPDSTATS) + (br * 3 + LAY - 1) * 128;
            k_pool<1><<<128, 256, 0, stream>>>(h, bat, updbuf[(LAY - 1) & 1], ustatsl,
                                               convNG + (LAY - 1) * 64, convNB + (LAY - 1) * 64,
                                               poolp, cntp, NNODE, 1.0f / NNODE);
        }
    }

    float* poolall = (float*)(ws + OFF_POOL);
    float* cntall = (float*)(ws + OFF_CNT);
    float* ystats = (float*)(ws + OFF_YSTATS);
    k_fc<<<64, 128, 0, stream>>>(poolall, cntall, (const float*)d_in[30], (const float*)d_in[31], Y, ystats);
    k_head<<<1, 128, 0, stream>>>(Y, ystats, (const float*)d_in[32], (const float*)d_in[33],
                                  (const float*)d_in[34], (const float*)d_in[35], (float*)d_out);
}